// Round 14
// baseline (861.320 us; speedup 1.0000x reference)
//
#include <hip/hip_runtime.h>

// ---------------------------------------------------------------------------
// DecoderLayer on MI355X. GEMM paths:
//  - k_gemm256 (4-phase, 256x256, BK=64, 1 block/CU): Wu (control arm).
//  - k_gemm_tall (256x128, BK=32, dbuf 48KB, launch_bounds(512,4) ->
//    2 blocks/CU target; simple 1-barrier loop): Wg (test arm).
//  - k_gemm_bt (128x128, BK=32, dbuf, granule-XOR swizzle): QKVZ, Wo, Wd.
// Attention: bf16 MFMA flash (unchanged).
// ---------------------------------------------------------------------------

typedef __attribute__((ext_vector_type(4))) float  f32x4;
typedef __attribute__((ext_vector_type(8))) short  s16x8;
typedef __attribute__((ext_vector_type(4))) unsigned short u16x4;

#define DEVI static __device__ __forceinline__

DEVI unsigned short f2bf(float f) {
  union { float f; unsigned u; } a; a.f = f;
  unsigned r = a.u + 0x7FFFu + ((a.u >> 16) & 1u);
  return (unsigned short)(r >> 16);
}
DEVI float bf2f(unsigned short u) {
  union { unsigned u; float f; } a; a.u = (unsigned)u << 16; return a.f;
}

DEVI void gload16(const void* g, void* l) {
  __builtin_amdgcn_global_load_lds(
      (const __attribute__((address_space(1))) unsigned int*)(unsigned long long)g,
      (__attribute__((address_space(3))) unsigned int*)(unsigned int)(unsigned long long)l,
      16, 0, 0);
}

#define MFMA_BF16 __builtin_amdgcn_mfma_f32_16x16x32_bf16
#define WAITV8()  asm volatile("s_waitcnt vmcnt(8)" ::: "memory")
#define WAITV0()  asm volatile("s_waitcnt vmcnt(0)" ::: "memory")
#define PIN()     __builtin_amdgcn_sched_barrier(0)
#define LGKM0()   do { asm volatile("s_waitcnt lgkmcnt(0)" ::: "memory"); \
                       __builtin_amdgcn_sched_barrier(0); } while (0)

// ---------------------------------------------------------------------------
__global__ void k_f32_to_bf16(const float* __restrict__ src,
                              unsigned short* __restrict__ dst, int n4) {
  int i = blockIdx.x * blockDim.x + threadIdx.x;
  int stride = gridDim.x * blockDim.x;
  for (; i < n4; i += stride) {
    f32x4 v = ((const f32x4*)src)[i];
    u16x4 o;
    o.x = f2bf(v.x); o.y = f2bf(v.y); o.z = f2bf(v.z); o.w = f2bf(v.w);
    ((u16x4*)dst)[i] = o;
  }
}

// ---------------------------------------------------------------------------
__global__ __launch_bounds__(256) void k_rmsnorm(const float* __restrict__ x,
                                                 const float* __restrict__ w,
                                                 unsigned short* __restrict__ out) {
  const int row = blockIdx.x, t = threadIdx.x;
  const f32x4* xr = (const f32x4*)(x + (size_t)row * 2048);
  f32x4 a = xr[t * 2], b = xr[t * 2 + 1];
  float ss = a.x*a.x + a.y*a.y + a.z*a.z + a.w*a.w
           + b.x*b.x + b.y*b.y + b.z*b.z + b.w*b.w;
#pragma unroll
  for (int m = 32; m; m >>= 1) ss += __shfl_xor(ss, m);
  __shared__ float sred[4];
  if ((t & 63) == 0) sred[t >> 6] = ss;
  __syncthreads();
  float tot = sred[0] + sred[1] + sred[2] + sred[3];
  float r = rsqrtf(tot * (1.0f / 2048.0f) + 1e-6f);
  const f32x4* wr = (const f32x4*)w;
  f32x4 w1 = wr[t * 2], w2 = wr[t * 2 + 1];
  u16x4 o1, o2;
  o1.x = f2bf(a.x * r * (1.f + w1.x)); o1.y = f2bf(a.y * r * (1.f + w1.y));
  o1.z = f2bf(a.z * r * (1.f + w1.z)); o1.w = f2bf(a.w * r * (1.f + w1.w));
  o2.x = f2bf(b.x * r * (1.f + w2.x)); o2.y = f2bf(b.y * r * (1.f + w2.y));
  o2.z = f2bf(b.z * r * (1.f + w2.z)); o2.w = f2bf(b.w * r * (1.f + w2.w));
  u16x4* od = (u16x4*)(out + (size_t)row * 2048);
  od[t * 2] = o1; od[t * 2 + 1] = o2;
}

// ---------------------------------------------------------------------------
__global__ void k_rope_table(float* __restrict__ cosT, float* __restrict__ sinT) {
  int i = blockIdx.x * blockDim.x + threadIdx.x;
  int tpos = i >> 6, f = i & 63;
  double inv = exp(-0.14391156831212787 * (double)f);
  float ang = (float)tpos * (float)inv;
  cosT[i] = cosf(ang);
  sinT[i] = sinf(ang);
}

// ---------------------------------------------------------------------------
__global__ __launch_bounds__(256) void k_qknorm_rope(
    const unsigned short* __restrict__ QKVZ,
    unsigned short* __restrict__ Qo, unsigned short* __restrict__ Ko,
    const float* __restrict__ qw, const float* __restrict__ kw,
    const float* __restrict__ cosT, const float* __restrict__ sinT) {
  int gid = blockIdx.x * 4 + (threadIdx.x >> 6);
  int lane = threadIdx.x & 63;
  int tok = gid / 20, hh = gid % 20;
  const unsigned short* p; const float* w; unsigned short* o;
  if (hh < 16) { p = QKVZ + (size_t)tok * 5120 + hh * 128; w = qw;
                 o = Qo + (size_t)tok * 2048 + hh * 128; }
  else         { p = QKVZ + (size_t)tok * 5120 + 2048 + (hh - 16) * 128; w = kw;
                 o = Ko + (size_t)tok * 512 + (hh - 16) * 128; }
  float x1 = bf2f(p[lane]), x2 = bf2f(p[lane + 64]);
  float ss = x1 * x1 + x2 * x2;
#pragma unroll
  for (int m = 1; m < 64; m <<= 1) ss += __shfl_xor(ss, m);
  float r = rsqrtf(ss * (1.0f / 128.0f) + 1e-6f);
  float n1 = x1 * r * (1.f + w[lane]);
  float n2 = x2 * r * (1.f + w[lane + 64]);
  int s = tok & 1023;
  float c = cosT[s * 64 + lane], sn = sinT[s * 64 + lane];
  o[lane]      = f2bf(n1 * c - n2 * sn);
  o[lane + 64] = f2bf(n2 * c + n1 * sn);
}

// ---------------------------------------------------------------------------
__global__ __launch_bounds__(256) void k_transpose_v(const unsigned short* __restrict__ QKVZ,
                                                     unsigned short* __restrict__ Vt) {
  __shared__ unsigned short Vl[128 * 66];
  const int t = threadIdx.x;
  const int key0 = blockIdx.x * 64, kvh = blockIdx.y, b = blockIdx.z;
#pragma unroll
  for (int i = 0; i < 4; ++i) {
    int g = i * 256 + t;
    int key = g >> 4, dc = (g & 15) * 8;
    s16x8 v = *(const s16x8*)&QKVZ[(size_t)(b * 1024 + key0 + key) * 5120 + 2560 + kvh * 128 + dc];
#pragma unroll
    for (int j = 0; j < 8; ++j) Vl[(dc + j) * 66 + key] = (unsigned short)v[j];
  }
  __syncthreads();
#pragma unroll
  for (int i = 0; i < 8; ++i) {
    int g = i * 256 + t;
    int d = g >> 4, kc = g & 15;
    u16x4 o;
#pragma unroll
    for (int j = 0; j < 4; ++j) o[j] = Vl[d * 66 + kc * 4 + j];
    *(u16x4*)&Vt[((size_t)(b * 4 + kvh) * 128 + d) * 1024 + key0 + kc * 4] = o;
  }
}

// ---------------------------------------------------------------------------
// 256x256 GEMM, BK=64, 8 waves, 4-phase/K-tile (r9 schedule). Wu control arm.
// EPI 2: store bf16.  EPI 4: in-place bf16( silu(Cb[idx]) * acc ).
// ---------------------------------------------------------------------------
template <int EPI>
__global__ __launch_bounds__(512) void k_gemm256(
    const unsigned short* __restrict__ A, const unsigned short* __restrict__ B,
    unsigned short* __restrict__ Cb, int M, int N, int K) {
  __shared__ unsigned short As[2][256][64];
  __shared__ unsigned short Bs[2][256][64];

  const int t = threadIdx.x, lane = t & 63, w = t >> 6;
  const int wr = w >> 2, wc = w & 3;
  const int l15 = lane & 15, l4 = lane >> 4;
  const int xg = l15 & 7;
  const int hb = wc >> 1, cl = wc & 1;

  const int nbx = gridDim.x;
  const int nwg = nbx * gridDim.y;
  const int bid = blockIdx.y * nbx + blockIdx.x;
  const int sw = (bid & 7) * (nwg >> 3) + (bid >> 3);
  const int tpg = 8 * nbx;
  const int mi_ = (sw / tpg) * 8 + (sw & 7);
  const int ni_ = (sw % tpg) >> 3;
  const int m0 = mi_ * 256, n0 = ni_ * 256;

  const int NT = K >> 6;

  auto stageA = [&](int tt, int pm) {
    int dd = tt & 1;
#pragma unroll
    for (int c = 0; c < 2; ++c) {
      int r0 = wr * 128 + pm * 64 + wc * 16 + c * 8;
      int r = r0 + (lane >> 3);
      int gs = (lane & 7) ^ (r & 7);
      gload16(A + (size_t)(m0 + r) * K + tt * 64 + gs * 8, (void*)&As[dd][r0][0]);
    }
  };
  auto stageB = [&](int tt, int pn) {
    int dd = tt & 1;
#pragma unroll
    for (int c = 0; c < 2; ++c) {
      int r0 = hb * 128 + cl * 64 + pn * 32 + wr * 16 + c * 8;
      int r = r0 + (lane >> 3);
      int gs = (lane & 7) ^ (r & 7);
      gload16(B + (size_t)(n0 + r) * K + tt * 64 + gs * 8, (void*)&Bs[dd][r0][0]);
    }
  };

  stageA(0, 0); stageB(0, 0); stageB(0, 1); stageA(0, 1);
  stageA(1, 0); stageB(1, 0); stageB(1, 1); stageA(1, 1);

  f32x4 acc[8][4] = {};

  WAITV8();
  __builtin_amdgcn_s_barrier();

  for (int u = 0; u < NT; ++u) {
    const int cur = u & 1;
    const bool deep = (u + 2 < NT);
    s16x8 afL[4][2], afH[4][2], bf0[2][2], bf1[2][2];

#pragma unroll
    for (int i = 0; i < 4; ++i) {
      int row = wr * 128 + i * 16 + l15;
      afL[i][0] = *(const s16x8*)&As[cur][row][(l4 ^ xg) * 8];
      afL[i][1] = *(const s16x8*)&As[cur][row][((l4 ^ xg) ^ 4) * 8];
    }
#pragma unroll
    for (int n = 0; n < 2; ++n) {
      int row = wc * 64 + n * 16 + l15;
      bf0[n][0] = *(const s16x8*)&Bs[cur][row][(l4 ^ xg) * 8];
      bf0[n][1] = *(const s16x8*)&Bs[cur][row][((l4 ^ xg) ^ 4) * 8];
    }
    PIN();
    __builtin_amdgcn_s_barrier();
    LGKM0();
    __builtin_amdgcn_s_setprio(1);
#pragma unroll
    for (int i = 0; i < 4; ++i)
#pragma unroll
      for (int n = 0; n < 2; ++n) {
        acc[i][n] = MFMA_BF16(afL[i][0], bf0[n][0], acc[i][n], 0, 0, 0);
        acc[i][n] = MFMA_BF16(afL[i][1], bf0[n][1], acc[i][n], 0, 0, 0);
      }
    __builtin_amdgcn_s_setprio(0);
    __builtin_amdgcn_s_barrier();

#pragma unroll
    for (int n = 0; n < 2; ++n) {
      int row = wc * 64 + (2 + n) * 16 + l15;
      bf1[n][0] = *(const s16x8*)&Bs[cur][row][(l4 ^ xg) * 8];
      bf1[n][1] = *(const s16x8*)&Bs[cur][row][((l4 ^ xg) ^ 4) * 8];
    }
    if (deep) stageA(u + 2, 0);
    PIN();
    __builtin_amdgcn_s_barrier();
    LGKM0();
    __builtin_amdgcn_s_setprio(1);
#pragma unroll
    for (int i = 0; i < 4; ++i)
#pragma unroll
      for (int n = 0; n < 2; ++n) {
        acc[i][2 + n] = MFMA_BF16(afL[i][0], bf1[n][0], acc[i][2 + n], 0, 0, 0);
        acc[i][2 + n] = MFMA_BF16(afL[i][1], bf1[n][1], acc[i][2 + n], 0, 0, 0);
      }
    __builtin_amdgcn_s_setprio(0);
    __builtin_amdgcn_s_barrier();

#pragma unroll
    for (int i = 0; i < 4; ++i) {
      int row = wr * 128 + 64 + i * 16 + l15;
      afH[i][0] = *(const s16x8*)&As[cur][row][(l4 ^ xg) * 8];
      afH[i][1] = *(const s16x8*)&As[cur][row][((l4 ^ xg) ^ 4) * 8];
    }
    if (deep) { stageB(u + 2, 0); stageB(u + 2, 1); }
    PIN();
    __builtin_amdgcn_s_barrier();
    LGKM0();
    __builtin_amdgcn_s_setprio(1);
#pragma unroll
    for (int i = 0; i < 4; ++i)
#pragma unroll
      for (int n = 0; n < 2; ++n) {
        acc[4 + i][2 + n] = MFMA_BF16(afH[i][0], bf1[n][0], acc[4 + i][2 + n], 0, 0, 0);
        acc[4 + i][2 + n] = MFMA_BF16(afH[i][1], bf1[n][1], acc[4 + i][2 + n], 0, 0, 0);
      }
    __builtin_amdgcn_s_setprio(0);
    __builtin_amdgcn_s_barrier();

    if (deep) stageA(u + 2, 1);
    if (deep) WAITV8(); else WAITV0();
    PIN();
    __builtin_amdgcn_s_barrier();
    __builtin_amdgcn_s_setprio(1);
#pragma unroll
    for (int i = 0; i < 4; ++i)
#pragma unroll
      for (int n = 0; n < 2; ++n) {
        acc[4 + i][n] = MFMA_BF16(afH[i][0], bf0[n][0], acc[4 + i][n], 0, 0, 0);
        acc[4 + i][n] = MFMA_BF16(afH[i][1], bf0[n][1], acc[4 + i][n], 0, 0, 0);
      }
    __builtin_amdgcn_s_setprio(0);
    __builtin_amdgcn_s_barrier();
  }

#pragma unroll
  for (int mi = 0; mi < 8; ++mi)
#pragma unroll
    for (int ni = 0; ni < 4; ++ni) {
      int col = n0 + wc * 64 + ni * 16 + l15;
#pragma unroll
      for (int j = 0; j < 4; ++j) {
        int row = m0 + wr * 128 + mi * 16 + l4 * 4 + j;
        size_t idx = (size_t)row * N + col;
        float g = acc[mi][ni][j];
        if constexpr (EPI == 2) {
          Cb[idx] = f2bf(g);
        } else {
          float gv = bf2f(Cb[idx]);
          float sg = gv / (1.f + __expf(-gv));
          Cb[idx] = f2bf(sg * g);
        }
      }
    }
}

// ---------------------------------------------------------------------------
// 256x128 GEMM, BK=32, 8 waves (4M x 2N, 64x64 each), dbuf 48KB LDS,
// launch_bounds(512,4) -> target 2 blocks/CU (cross-block overlap hides the
// barrier drain). Simple 1-barrier/K-step loop (k_gemm_bt template).
// Granule swizzle: stage src granule (lane&3)^((lane>>2)&3); read l4^(l15&3).
// EPI 2: store bf16.
// ---------------------------------------------------------------------------
template <int EPI>
__global__ __launch_bounds__(512, 4) void k_gemm_tall(
    const unsigned short* __restrict__ A, const unsigned short* __restrict__ B,
    unsigned short* __restrict__ Cb, int M, int N, int K) {
  __shared__ unsigned short As[2][256][32];
  __shared__ unsigned short Bs[2][128][32];

  const int t = threadIdx.x, lane = t & 63, w = t >> 6;
  const int wr = w >> 1, wc = w & 1;        // 4M x 2N wave grid
  const int l15 = lane & 15, l4 = lane >> 4;

  const int nbx = gridDim.x;
  const int nwg = nbx * gridDim.y;
  const int bid = blockIdx.y * nbx + blockIdx.x;
  const int sw = (bid & 7) * (nwg >> 3) + (bid >> 3);
  const int tpg = 8 * nbx;
  const int mi_ = (sw / tpg) * 8 + (sw & 7);
  const int ni_ = (sw % tpg) >> 3;
  const int m0 = mi_ * 256, n0 = ni_ * 128;

  f32x4 acc[4][4] = {};

  const int srow = lane >> 2;                       // 0..15
  const int sg = ((lane & 3) ^ (srow & 3)) * 8;     // pre-swizzled src granule
  const int rg = (l4 ^ (l15 & 3)) * 8;              // read granule

  auto stage = [&](int kk, int sel) {
#pragma unroll
    for (int c = 0; c < 2; ++c) {
      int r0 = w * 32 + c * 16;
      gload16(A + (size_t)(m0 + r0 + srow) * K + kk + sg, (void*)&As[sel][r0][0]);
    }
    int rb = w * 16;
    gload16(B + (size_t)(n0 + rb + srow) * K + kk + sg, (void*)&Bs[sel][rb][0]);
  };

  stage(0, 0);
  __syncthreads();

  const int nk = K >> 5;
  for (int tk = 0; tk < nk; ++tk) {
    const int cur = tk & 1;
    if (tk + 1 < nk) stage((tk + 1) << 5, cur ^ 1);

    s16x8 bf_[4];
#pragma unroll
    for (int n = 0; n < 4; ++n)
      bf_[n] = *(const s16x8*)&Bs[cur][wc * 64 + n * 16 + l15][rg];
#pragma unroll
    for (int mi2 = 0; mi2 < 4; ++mi2) {
      s16x8 af = *(const s16x8*)&As[cur][wr * 64 + mi2 * 16 + l15][rg];
#pragma unroll
      for (int ni2 = 0; ni2 < 4; ++ni2)
        acc[mi2][ni2] = MFMA_BF16(af, bf_[ni2], acc[mi2][ni2], 0, 0, 0);
    }
    __syncthreads();
  }

  const int er = (lane >> 4) * 4;
  const int ec = lane & 15;
#pragma unroll
  for (int mi2 = 0; mi2 < 4; ++mi2)
#pragma unroll
    for (int ni2 = 0; ni2 < 4; ++ni2) {
      int col = n0 + wc * 64 + ni2 * 16 + ec;
#pragma unroll
      for (int j = 0; j < 4; ++j) {
        int row = m0 + wr * 64 + mi2 * 16 + er + j;
        size_t idx = (size_t)row * N + col;
        Cb[idx] = f2bf(acc[mi2][ni2][j]);
      }
    }
}

// ---------------------------------------------------------------------------
// 128x128 2-phase dbuf GEMM with granule-XOR swizzle (QKVZ / Wo / Wd).
// EPI 0: f32. EPI 1: f32 + residual. EPI 2: bf16.
// ---------------------------------------------------------------------------
template <int EPI>
__global__ __launch_bounds__(256) void k_gemm_bt(
    const unsigned short* __restrict__ A, const unsigned short* __restrict__ B,
    float* __restrict__ Cf, unsigned short* __restrict__ Cb,
    const float* __restrict__ res,
    int M, int N, int K) {
  __shared__ unsigned short As[2][128 * 32];
  __shared__ unsigned short Bs[2][128 * 32];

  const int t = threadIdx.x, lane = t & 63, w = t >> 6;
  const int wr = w >> 1, wc = w & 1;
  const int l15 = lane & 15, l4 = lane >> 4;
  const int nbx = gridDim.x;
  const int nwg = nbx * gridDim.y;
  const int bid = blockIdx.y * nbx + blockIdx.x;
  const int sw = (bid & 7) * (nwg >> 3) + (bid >> 3);
  const int tpg = 8 * nbx;
  const int mi = (sw / tpg) * 8 + (sw & 7);
  const int ni = (sw % tpg) >> 3;
  const int m0 = mi * 128, n0 = ni * 128;

  f32x4 acc[4][4] = {};

  const int srow = lane >> 2;
  const int scol = (((lane & 3) ^ (srow & 3))) * 8;
  const int rg = (l4 ^ (l15 & 3)) * 8;

  auto stage = [&](int kk, int sel) {
#pragma unroll
    for (int r = 0; r < 2; ++r) {
      int row = 16 * w + srow + 64 * r;
      gload16(A + (size_t)(m0 + row) * K + kk + scol, (void*)&As[sel][w * 512 + r * 2048]);
      gload16(B + (size_t)(n0 + row) * K + kk + scol, (void*)&Bs[sel][w * 512 + r * 2048]);
    }
  };

  stage(0, 0);
  __syncthreads();

  const int nk = K >> 5;
  for (int tk = 0; tk < nk; ++tk) {
    const int cur = tk & 1;
    if (tk + 1 < nk) stage((tk + 1) << 5, cur ^ 1);

    s16x8 af[4], bf_[4];
#pragma unroll
    for (int i = 0; i < 4; ++i) {
      af[i]  = *(const s16x8*)&As[cur][(wr * 64 + i * 16 + l15) * 32 + rg];
      bf_[i] = *(const s16x8*)&Bs[cur][(wc * 64 + i * 16 + l15) * 32 + rg];
    }
#pragma unroll
    for (int mi2 = 0; mi2 < 4; ++mi2)
#pragma unroll
      for (int ni2 = 0; ni2 < 4; ++ni2)
        acc[mi2][ni2] = MFMA_BF16(af[mi2], bf_[ni2], acc[mi2][ni2], 0, 0, 0);
    __syncthreads();
  }

  const int er = (lane >> 4) * 4;
  const int ec = lane & 15;
#pragma unroll
  for (int mi2 = 0; mi2 < 4; ++mi2)
#pragma unroll
    for (int ni2 = 0; ni2 < 4; ++ni2) {
      int col = n0 + wc * 64 + ni2 * 16 + ec;
#pragma unroll
      for (int j = 0; j < 4; ++j) {
        int row = m0 + wr * 64 + mi2 * 16 + er + j;
        size_t idx = (size_t)row * N + col;
        float g = acc[mi2][ni2][j];
        if constexpr (EPI == 0) {
          Cf[idx] = g;
        } else if constexpr (EPI == 1) {
          Cf[idx] = g + res[idx];
        } else if constexpr (EPI == 2) {
          Cb[idx] = f2bf(g);
        } else {
          float gv = bf2f(Cb[idx]);
          float sg = gv / (1.f + __expf(-gv));
          Cb[idx] = f2bf(sg * g);
        }
      }
    }
}

// ---------------------------------------------------------------------------
// Causal GQA attention, bf16 MFMA flash (unchanged).
// ---------------------------------------------------------------------------
__global__ __launch_bounds__(256) void k_attn_mfma(
    const unsigned short* __restrict__ Qb,
    const unsigned short* __restrict__ Kb,
    const unsigned short* __restrict__ Vt,
    const unsigned short* __restrict__ Zb,
    unsigned short* __restrict__ AO) {
  __shared__ unsigned short Qs[64 * 128];
  __shared__ unsigned short Ks[64 * 128];
  __shared__ unsigned short Vts[128 * 64];
  __shared__ unsigned short Ps[4][16 * 64];

  const int t = threadIdx.x, lane = t & 63, w = t >> 6;
  const int l15 = lane & 15, l4 = lane >> 4;
  const int qt = (int)gridDim.x - 1 - (int)blockIdx.x;
  const int qs0 = qt * 64;
  const int h = blockIdx.y, b = blockIdx.z;
  const int kv = h >> 2;

  {
    const unsigned short* qb = Qb + (size_t)(b * 1024 + qs0) * 2048 + h * 128;
#pragma unroll
    for (int r = 0; r < 4; ++r) {
      int row = r * 16 + w * 4 + (lane >> 4);
      int cp = lane & 15;
      int c = (cp & 8) | ((cp & 7) ^ (row & 7));
      gload16(qb + (size_t)row * 2048 + c * 8, (void*)&Qs[(r * 256 + w * 64) * 8]);
    }
  }

  auto stageKV = [&](int j0) {
    const unsigned short* kb = Kb + (size_t)(b * 1024 + j0) * 512 + kv * 128;
#pragma unroll
    for (int r = 0; r < 4; ++r) {
      int row = r * 16 + w * 4 + (lane >> 4);
      int cp = lane & 15;
      int c = (cp & 8) | ((cp & 7) ^ (row & 7));
      gload16(kb + (size_t)row * 512 + c * 8, (void*)&Ks[(r * 256 + w * 64) * 8]);
    }
    const unsigned short* vb = Vt + (size_t)(b * 4 + kv) * 131072 + j0;
#pragma unroll
    for (int r = 0; r < 4; ++r) {
      int row = r * 32 + w * 8 + (lane >> 3);
      int cp = lane & 7;
      int c = cp ^ (row & 7);
      gload16(vb + (size_t)row * 1024 + c * 8, (void*)&Vts[(r * 256 + w * 64) * 8]);
    }
  };

  stageKV(0);
  __syncthreads();

  s16x8 qf[4];
#pragma unroll
  for (int ks = 0; ks < 4; ++ks) {
    int R = w * 16 + l15;
    int c = ks * 4 + l4;
    int cp = (c & 8) | ((c & 7) ^ (R & 7));
    qf[ks] = *(const s16x8*)&Qs[R * 128 + cp * 8];
  }

  f32x4 O[8] = {};
  f32x4 mrow = {-1e30f, -1e30f, -1e30f, -1e30f};
  f32x4 lrow = {0.f, 0.f, 0.f, 0.f};
  const float scale = 0.088388347648318447f;

  for (int tile = 0; tile <= qt; ++tile) {
    f32x4 sc[4] = {};
#pragma unroll
    for (int ks = 0; ks < 4; ++ks) {
#pragma unroll
      for (int kt = 0; kt < 4; ++kt) {
        int R = kt * 16 + l15;
        int c = ks * 4 + l4;
        int cp = (c & 8) | ((c & 7) ^ (R & 7));
        s16x8 kf = *(const s16x8*)&Ks[R * 128 + cp * 8];
        sc[kt] = MFMA_BF16(qf[ks], kf, sc[kt], 0, 0, 0);
      }
    }
    const bool diag = (tile == qt);
#pragma unroll
    for (int kt = 0; kt < 4; ++kt) {
      int key = kt * 16 + l15;
#pragma unroll
      for (int j = 0; j < 4; ++j) {
        float s = sc[kt][j] * scale;
        if (diag && key > (w * 16 + l4 * 4 + j)) s = -1e30f;
        sc[kt][j] = s;
      }
    }
    f32x4 mt;
#pragma unroll
    for (int j = 0; j < 4; ++j)
      mt[j] = fmaxf(fmaxf(sc[0][j], sc[1][j]), fmaxf(sc[2][j], sc[3][j]));
#pragma unroll
    for (int msk = 1; msk < 16; msk <<= 1)
#pragma unroll
      for (int j = 0; j < 4; ++j) mt[j] = fmaxf(mt[j], __shfl_xor(mt[j], msk));
    f32x4 mnew, rs;
#pragma unroll
    for (int j = 0; j < 4; ++j) {
      mnew[j] = fmaxf(mrow[j], mt[j]);
      rs[j] = __expf(mrow[j] - mnew[j]);
    }
    f32x4 psum = {0.f, 0.f, 0.f, 0.f};
    unsigned short* pw = &Ps[w][0];
#pragma unroll
    for (int kt = 0; kt < 4; ++kt) {
      int kg = kt * 2 + (l15 >> 3), ke = l15 & 7;
#pragma unroll
      for (int j = 0; j < 4; ++j) {
        float p = __expf(sc[kt][j] - mnew[j]);
        psum[j] += p;
        int q = l4 * 4 + j;
        pw[q * 64 + ((kg ^ (q & 7)) * 8) + ke] = f2bf(p);
      }
    }
#pragma unroll
    for (int msk = 1; msk < 16; msk <<= 1)
#pragma unroll
      for (int j = 0; j < 4; ++j) psum[j] += __shfl_xor(psum[j], msk);
    mrow = mnew;
#pragma unroll
    for (int j = 0; j < 4; ++j) lrow[j] = lrow[j] * rs[j] + psum[j];
#pragma unroll
    for (int dt = 0; dt < 8; ++dt) O[dt] *= rs;
#pragma unroll
    for (int js = 0; js < 2; ++js) {
      int cpp = (js * 4 + l4) ^ (l15 & 7);
      s16x8 pf = *(const s16x8*)&Ps[w][l15 * 64 + cpp * 8];
#pragma unroll
      for (int dt = 0; dt < 8; ++dt) {
        int D = dt * 16 + l15;
        s16x8 vf = *(const s16x8*)&Vts[D * 64 + cpp * 8];
        O[dt] = MFMA_BF16(pf, vf, O[dt], 0, 0, 0);
      }
    }
    __syncthreads();
    if (tile < qt) stageKV((tile + 1) * 64);
    __syncthreads();
  }

  f32x4 linv;
#pragma unroll
  for (int j = 0; j < 4; ++j) linv[j] = 1.f / lrow[j];
  const int tok0 = b * 1024 + qs0 + w * 16 + l4 * 4;
#pragma unroll
  for (int dt = 0; dt < 8; ++dt) {
    int d = dt * 16 + l15;
#pragma unroll
    for (int j = 0; j < 4; ++j) {
      size_t zidx = (size_t)(tok0 + j) * 5120 + h * 128 + d;
      size_t aidx = (size_t)(tok0 + j) * 2048 + h * 128 + d;
      float z = bf2f(Zb[zidx]);
      float o = O[dt][j] * linv[j];
      AO[aidx] = f2bf(o / (1.f + __expf(-z)));
    }
  }
}

// ---------------------------------------------------------------------------
// launcher
// ---------------------------------------------------------------------------
extern "C" void kernel_launch(void* const* d_in, const int* in_sizes, int n_in,
                              void* d_out, int out_size, void* d_ws, size_t ws_size,
                              hipStream_t stream) {
  const float* x       = (const float*)d_in[0];
  const float* in_ln   = (const float*)d_in[1];
  const float* Wq      = (const float*)d_in[2];
  const float* Wk      = (const float*)d_in[3];
  const float* Wv      = (const float*)d_in[4];
  const float* Wz      = (const float*)d_in[5];
  const float* Wo      = (const float*)d_in[6];
  const float* qn_w    = (const float*)d_in[7];
  const float* kn_w    = (const float*)d_in[8];
  const float* post_ln = (const float*)d_in[9];
  const float* Wg      = (const float*)d_in[10];
  const float* Wu      = (const float*)d_in[11];
  const float* Wd      = (const float*)d_in[12];

  const int T = 4096;

  char* ws = (char*)d_ws;
  size_t off = 0;
  auto alloc = [&](size_t bytes) -> void* {
    off = (off + 255) & ~(size_t)255;
    void* p = ws + off;
    off += bytes;
    return p;
  };

  unsigned short* Wqkvz_b = (unsigned short*)alloc((size_t)5120 * 2048 * 2);
  unsigned short* Wo_b = (unsigned short*)alloc((size_t)2048 * 2048 * 2);
  unsigned short* Wg_b = (unsigned short*)alloc((size_t)8192 * 2048 * 2);
  unsigned short* Wu_b = (unsigned short*)alloc((size_t)8192 * 2048 * 2);
  unsigned short* Wd_b = (unsigned short*)alloc((size_t)2048 * 8192 * 2);

  char* R = (char*)alloc((size_t)64 * 1024 * 1024);
  unsigned short* qkvz_bf = (unsigned short*)R;
  unsigned short* h_bf    = (unsigned short*)(R + (size_t)40 * 1024 * 1024);
  unsigned short* gu_bf   = (unsigned short*)R;
  unsigned short* ao_bf   = h_bf;

  float* x2 = (float*)alloc((size_t)T * 2048 * 4);
  char* x2c = (char*)x2;
  unsigned short* vt_bf = (unsigned short*)(x2c);
  unsigned short* k_bf  = (unsigned short*)(x2c + 4194304);
  unsigned short* q_bf  = (unsigned short*)(x2c + 8388608);

  unsigned short* h2_bf = (unsigned short*)alloc((size_t)T * 2048 * 2);
  float* cosT = (float*)alloc((size_t)1024 * 64 * 4);
  float* sinT = (float*)alloc((size_t)1024 * 64 * 4);

  auto cvt = [&](const float* s, unsigned short* d, size_t n) {
    int n4 = (int)(n / 4);
    int blocks = (n4 + 255) / 256;
    if (blocks > 2048) blocks = 2048;
    k_f32_to_bf16<<<blocks, 256, 0, stream>>>(s, d, n4);
  };
  cvt(Wq, Wqkvz_b, (size_t)2048 * 2048);
  cvt(Wk, Wqkvz_b + (size_t)2048 * 2048, (size_t)512 * 2048);
  cvt(Wv, Wqkvz_b + (size_t)2560 * 2048, (size_t)512 * 2048);
  cvt(Wz, Wqkvz_b + (size_t)3072 * 2048, (size_t)2048 * 2048);
  cvt(Wo, Wo_b, (size_t)2048 * 2048);
  cvt(Wg, Wg_b, (size_t)8192 * 2048);
  cvt(Wu, Wu_b, (size_t)8192 * 2048);
  cvt(Wd, Wd_b, (size_t)2048 * 8192);

  k_rope_table<<<256, 256, 0, stream>>>(cosT, sinT);

  // h = rmsnorm(x, in_ln)
  k_rmsnorm<<<T, 256, 0, stream>>>(x, in_ln, h_bf);

  // fused QKVZ projection: [4096][5120] bf16 (128² dbuf)
  k_gemm_bt<2><<<dim3(40, 32), 256, 0, stream>>>(h_bf, Wqkvz_b, nullptr, qkvz_bf, nullptr, T, 5120, 2048);

  // per-head q/k RMSNorm + RoPE -> bf16
  k_qknorm_rope<<<20480, 256, 0, stream>>>(qkvz_bf, q_bf, k_bf, qn_w, kn_w, cosT, sinT);

  // V -> V^T bf16 per (b,kv)
  k_transpose_v<<<dim3(16, 4, 4), 256, 0, stream>>>(qkvz_bf, vt_bf);

  // causal GQA attention (MFMA) + sigmoid(z) gate -> ao_bf
  k_attn_mfma<<<dim3(16, 16, 4), 256, 0, stream>>>(q_bf, k_bf, vt_bf, qkvz_bf + 3072, ao_bf);

  // x2 = x + ao @ Wo^T
  k_gemm_bt<1><<<dim3(16, 32), 256, 0, stream>>>(ao_bf, Wo_b, x2, nullptr, x, T, 2048, 2048);

  // h2 = rmsnorm(x2, post_ln)
  k_rmsnorm<<<T, 256, 0, stream>>>(x2, post_ln, h2_bf);

  // gu = h2 @ Wg^T  (bf16) -- 256x128 2-blocks/CU test arm
  k_gemm_tall<2><<<dim3(64, 16), 512, 0, stream>>>(h2_bf, Wg_b, gu_bf, T, 8192, 2048);

  // gu = silu(gu) * (h2 @ Wu^T)  (in place) -- 4-phase 256² control arm
  k_gemm256<4><<<dim3(32, 16), 512, 0, stream>>>(h2_bf, Wu_b, gu_bf, T, 8192, 2048);

  // out = x2 + gu @ Wd^T  (128² dbuf)
  k_gemm_bt<1><<<dim3(16, 32), 256, 0, stream>>>(gu_bf, Wd_b, (float*)d_out, nullptr, x2, T, 2048, 8192);
}

// Round 15
// 841.834 us; speedup vs baseline: 1.0231x; 1.0231x over previous
//
#include <hip/hip_runtime.h>

// ---------------------------------------------------------------------------
// DecoderLayer on MI355X — best-known configuration (r13, 839 us):
//  - k_gemm256 (4-phase, 256x256, BK=64, XOR-swizzle, setprio): Wg, Wu.
//  - k_gemm_bt (128x128, BK=32, dbuf, supertile raster): QKVZ, Wo, Wd.
//  - k_attn_mfma: bf16 MFMA flash attention with fused sigmoid(z) gate.
// ---------------------------------------------------------------------------

typedef __attribute__((ext_vector_type(4))) float  f32x4;
typedef __attribute__((ext_vector_type(8))) short  s16x8;
typedef __attribute__((ext_vector_type(4))) unsigned short u16x4;

#define DEVI static __device__ __forceinline__

DEVI unsigned short f2bf(float f) {
  union { float f; unsigned u; } a; a.f = f;
  unsigned r = a.u + 0x7FFFu + ((a.u >> 16) & 1u);
  return (unsigned short)(r >> 16);
}
DEVI float bf2f(unsigned short u) {
  union { unsigned u; float f; } a; a.u = (unsigned)u << 16; return a.f;
}

DEVI void gload16(const void* g, void* l) {
  __builtin_amdgcn_global_load_lds(
      (const __attribute__((address_space(1))) unsigned int*)(unsigned long long)g,
      (__attribute__((address_space(3))) unsigned int*)(unsigned int)(unsigned long long)l,
      16, 0, 0);
}

#define MFMA_BF16 __builtin_amdgcn_mfma_f32_16x16x32_bf16
#define WAITV8()  asm volatile("s_waitcnt vmcnt(8)" ::: "memory")
#define WAITV0()  asm volatile("s_waitcnt vmcnt(0)" ::: "memory")
#define PIN()     __builtin_amdgcn_sched_barrier(0)
#define LGKM0()   do { asm volatile("s_waitcnt lgkmcnt(0)" ::: "memory"); \
                       __builtin_amdgcn_sched_barrier(0); } while (0)

// ---------------------------------------------------------------------------
__global__ void k_f32_to_bf16(const float* __restrict__ src,
                              unsigned short* __restrict__ dst, int n4) {
  int i = blockIdx.x * blockDim.x + threadIdx.x;
  int stride = gridDim.x * blockDim.x;
  for (; i < n4; i += stride) {
    f32x4 v = ((const f32x4*)src)[i];
    u16x4 o;
    o.x = f2bf(v.x); o.y = f2bf(v.y); o.z = f2bf(v.z); o.w = f2bf(v.w);
    ((u16x4*)dst)[i] = o;
  }
}

// ---------------------------------------------------------------------------
__global__ __launch_bounds__(256) void k_rmsnorm(const float* __restrict__ x,
                                                 const float* __restrict__ w,
                                                 unsigned short* __restrict__ out) {
  const int row = blockIdx.x, t = threadIdx.x;
  const f32x4* xr = (const f32x4*)(x + (size_t)row * 2048);
  f32x4 a = xr[t * 2], b = xr[t * 2 + 1];
  float ss = a.x*a.x + a.y*a.y + a.z*a.z + a.w*a.w
           + b.x*b.x + b.y*b.y + b.z*b.z + b.w*b.w;
#pragma unroll
  for (int m = 32; m; m >>= 1) ss += __shfl_xor(ss, m);
  __shared__ float sred[4];
  if ((t & 63) == 0) sred[t >> 6] = ss;
  __syncthreads();
  float tot = sred[0] + sred[1] + sred[2] + sred[3];
  float r = rsqrtf(tot * (1.0f / 2048.0f) + 1e-6f);
  const f32x4* wr = (const f32x4*)w;
  f32x4 w1 = wr[t * 2], w2 = wr[t * 2 + 1];
  u16x4 o1, o2;
  o1.x = f2bf(a.x * r * (1.f + w1.x)); o1.y = f2bf(a.y * r * (1.f + w1.y));
  o1.z = f2bf(a.z * r * (1.f + w1.z)); o1.w = f2bf(a.w * r * (1.f + w1.w));
  o2.x = f2bf(b.x * r * (1.f + w2.x)); o2.y = f2bf(b.y * r * (1.f + w2.y));
  o2.z = f2bf(b.z * r * (1.f + w2.z)); o2.w = f2bf(b.w * r * (1.f + w2.w));
  u16x4* od = (u16x4*)(out + (size_t)row * 2048);
  od[t * 2] = o1; od[t * 2 + 1] = o2;
}

// ---------------------------------------------------------------------------
__global__ void k_rope_table(float* __restrict__ cosT, float* __restrict__ sinT) {
  int i = blockIdx.x * blockDim.x + threadIdx.x;
  int tpos = i >> 6, f = i & 63;
  double inv = exp(-0.14391156831212787 * (double)f);
  float ang = (float)tpos * (float)inv;
  cosT[i] = cosf(ang);
  sinT[i] = sinf(ang);
}

// ---------------------------------------------------------------------------
__global__ __launch_bounds__(256) void k_qknorm_rope(
    const unsigned short* __restrict__ QKVZ,
    unsigned short* __restrict__ Qo, unsigned short* __restrict__ Ko,
    const float* __restrict__ qw, const float* __restrict__ kw,
    const float* __restrict__ cosT, const float* __restrict__ sinT) {
  int gid = blockIdx.x * 4 + (threadIdx.x >> 6);
  int lane = threadIdx.x & 63;
  int tok = gid / 20, hh = gid % 20;
  const unsigned short* p; const float* w; unsigned short* o;
  if (hh < 16) { p = QKVZ + (size_t)tok * 5120 + hh * 128; w = qw;
                 o = Qo + (size_t)tok * 2048 + hh * 128; }
  else         { p = QKVZ + (size_t)tok * 5120 + 2048 + (hh - 16) * 128; w = kw;
                 o = Ko + (size_t)tok * 512 + (hh - 16) * 128; }
  float x1 = bf2f(p[lane]), x2 = bf2f(p[lane + 64]);
  float ss = x1 * x1 + x2 * x2;
#pragma unroll
  for (int m = 1; m < 64; m <<= 1) ss += __shfl_xor(ss, m);
  float r = rsqrtf(ss * (1.0f / 128.0f) + 1e-6f);
  float n1 = x1 * r * (1.f + w[lane]);
  float n2 = x2 * r * (1.f + w[lane + 64]);
  int s = tok & 1023;
  float c = cosT[s * 64 + lane], sn = sinT[s * 64 + lane];
  o[lane]      = f2bf(n1 * c - n2 * sn);
  o[lane + 64] = f2bf(n2 * c + n1 * sn);
}

// ---------------------------------------------------------------------------
__global__ __launch_bounds__(256) void k_transpose_v(const unsigned short* __restrict__ QKVZ,
                                                     unsigned short* __restrict__ Vt) {
  __shared__ unsigned short Vl[128 * 66];
  const int t = threadIdx.x;
  const int key0 = blockIdx.x * 64, kvh = blockIdx.y, b = blockIdx.z;
#pragma unroll
  for (int i = 0; i < 4; ++i) {
    int g = i * 256 + t;
    int key = g >> 4, dc = (g & 15) * 8;
    s16x8 v = *(const s16x8*)&QKVZ[(size_t)(b * 1024 + key0 + key) * 5120 + 2560 + kvh * 128 + dc];
#pragma unroll
    for (int j = 0; j < 8; ++j) Vl[(dc + j) * 66 + key] = (unsigned short)v[j];
  }
  __syncthreads();
#pragma unroll
  for (int i = 0; i < 8; ++i) {
    int g = i * 256 + t;
    int d = g >> 4, kc = g & 15;
    u16x4 o;
#pragma unroll
    for (int j = 0; j < 4; ++j) o[j] = Vl[d * 66 + kc * 4 + j];
    *(u16x4*)&Vt[((size_t)(b * 4 + kvh) * 128 + d) * 1024 + key0 + kc * 4] = o;
  }
}

// ---------------------------------------------------------------------------
// 256x256 GEMM, BK=64, 8 waves, 4-phase/K-tile. Wg + Wu.
// EPI 2: store bf16.  EPI 4: in-place bf16( silu(Cb[idx]) * acc ).
// ---------------------------------------------------------------------------
template <int EPI>
__global__ __launch_bounds__(512) void k_gemm256(
    const unsigned short* __restrict__ A, const unsigned short* __restrict__ B,
    unsigned short* __restrict__ Cb, int M, int N, int K) {
  __shared__ unsigned short As[2][256][64];
  __shared__ unsigned short Bs[2][256][64];

  const int t = threadIdx.x, lane = t & 63, w = t >> 6;
  const int wr = w >> 2, wc = w & 3;
  const int l15 = lane & 15, l4 = lane >> 4;
  const int xg = l15 & 7;
  const int hb = wc >> 1, cl = wc & 1;

  const int nbx = gridDim.x;
  const int nwg = nbx * gridDim.y;
  const int bid = blockIdx.y * nbx + blockIdx.x;
  const int sw = (bid & 7) * (nwg >> 3) + (bid >> 3);
  const int tpg = 8 * nbx;
  const int mi_ = (sw / tpg) * 8 + (sw & 7);
  const int ni_ = (sw % tpg) >> 3;
  const int m0 = mi_ * 256, n0 = ni_ * 256;

  const int NT = K >> 6;

  auto stageA = [&](int tt, int pm) {
    int dd = tt & 1;
#pragma unroll
    for (int c = 0; c < 2; ++c) {
      int r0 = wr * 128 + pm * 64 + wc * 16 + c * 8;
      int r = r0 + (lane >> 3);
      int gs = (lane & 7) ^ (r & 7);
      gload16(A + (size_t)(m0 + r) * K + tt * 64 + gs * 8, (void*)&As[dd][r0][0]);
    }
  };
  auto stageB = [&](int tt, int pn) {
    int dd = tt & 1;
#pragma unroll
    for (int c = 0; c < 2; ++c) {
      int r0 = hb * 128 + cl * 64 + pn * 32 + wr * 16 + c * 8;
      int r = r0 + (lane >> 3);
      int gs = (lane & 7) ^ (r & 7);
      gload16(B + (size_t)(n0 + r) * K + tt * 64 + gs * 8, (void*)&Bs[dd][r0][0]);
    }
  };

  stageA(0, 0); stageB(0, 0); stageB(0, 1); stageA(0, 1);
  stageA(1, 0); stageB(1, 0); stageB(1, 1); stageA(1, 1);

  f32x4 acc[8][4] = {};

  WAITV8();
  __builtin_amdgcn_s_barrier();

  for (int u = 0; u < NT; ++u) {
    const int cur = u & 1;
    const bool deep = (u + 2 < NT);
    s16x8 afL[4][2], afH[4][2], bf0[2][2], bf1[2][2];

#pragma unroll
    for (int i = 0; i < 4; ++i) {
      int row = wr * 128 + i * 16 + l15;
      afL[i][0] = *(const s16x8*)&As[cur][row][(l4 ^ xg) * 8];
      afL[i][1] = *(const s16x8*)&As[cur][row][((l4 ^ xg) ^ 4) * 8];
    }
#pragma unroll
    for (int n = 0; n < 2; ++n) {
      int row = wc * 64 + n * 16 + l15;
      bf0[n][0] = *(const s16x8*)&Bs[cur][row][(l4 ^ xg) * 8];
      bf0[n][1] = *(const s16x8*)&Bs[cur][row][((l4 ^ xg) ^ 4) * 8];
    }
    PIN();
    __builtin_amdgcn_s_barrier();
    LGKM0();
    __builtin_amdgcn_s_setprio(1);
#pragma unroll
    for (int i = 0; i < 4; ++i)
#pragma unroll
      for (int n = 0; n < 2; ++n) {
        acc[i][n] = MFMA_BF16(afL[i][0], bf0[n][0], acc[i][n], 0, 0, 0);
        acc[i][n] = MFMA_BF16(afL[i][1], bf0[n][1], acc[i][n], 0, 0, 0);
      }
    __builtin_amdgcn_s_setprio(0);
    __builtin_amdgcn_s_barrier();

#pragma unroll
    for (int n = 0; n < 2; ++n) {
      int row = wc * 64 + (2 + n) * 16 + l15;
      bf1[n][0] = *(const s16x8*)&Bs[cur][row][(l4 ^ xg) * 8];
      bf1[n][1] = *(const s16x8*)&Bs[cur][row][((l4 ^ xg) ^ 4) * 8];
    }
    if (deep) stageA(u + 2, 0);
    PIN();
    __builtin_amdgcn_s_barrier();
    LGKM0();
    __builtin_amdgcn_s_setprio(1);
#pragma unroll
    for (int i = 0; i < 4; ++i)
#pragma unroll
      for (int n = 0; n < 2; ++n) {
        acc[i][2 + n] = MFMA_BF16(afL[i][0], bf1[n][0], acc[i][2 + n], 0, 0, 0);
        acc[i][2 + n] = MFMA_BF16(afL[i][1], bf1[n][1], acc[i][2 + n], 0, 0, 0);
      }
    __builtin_amdgcn_s_setprio(0);
    __builtin_amdgcn_s_barrier();

#pragma unroll
    for (int i = 0; i < 4; ++i) {
      int row = wr * 128 + 64 + i * 16 + l15;
      afH[i][0] = *(const s16x8*)&As[cur][row][(l4 ^ xg) * 8];
      afH[i][1] = *(const s16x8*)&As[cur][row][((l4 ^ xg) ^ 4) * 8];
    }
    if (deep) { stageB(u + 2, 0); stageB(u + 2, 1); }
    PIN();
    __builtin_amdgcn_s_barrier();
    LGKM0();
    __builtin_amdgcn_s_setprio(1);
#pragma unroll
    for (int i = 0; i < 4; ++i)
#pragma unroll
      for (int n = 0; n < 2; ++n) {
        acc[4 + i][2 + n] = MFMA_BF16(afH[i][0], bf1[n][0], acc[4 + i][2 + n], 0, 0, 0);
        acc[4 + i][2 + n] = MFMA_BF16(afH[i][1], bf1[n][1], acc[4 + i][2 + n], 0, 0, 0);
      }
    __builtin_amdgcn_s_setprio(0);
    __builtin_amdgcn_s_barrier();

    if (deep) stageA(u + 2, 1);
    if (deep) WAITV8(); else WAITV0();
    PIN();
    __builtin_amdgcn_s_barrier();
    __builtin_amdgcn_s_setprio(1);
#pragma unroll
    for (int i = 0; i < 4; ++i)
#pragma unroll
      for (int n = 0; n < 2; ++n) {
        acc[4 + i][n] = MFMA_BF16(afH[i][0], bf0[n][0], acc[4 + i][n], 0, 0, 0);
        acc[4 + i][n] = MFMA_BF16(afH[i][1], bf0[n][1], acc[4 + i][n], 0, 0, 0);
      }
    __builtin_amdgcn_s_setprio(0);
    __builtin_amdgcn_s_barrier();
  }

#pragma unroll
  for (int mi = 0; mi < 8; ++mi)
#pragma unroll
    for (int ni = 0; ni < 4; ++ni) {
      int col = n0 + wc * 64 + ni * 16 + l15;
#pragma unroll
      for (int j = 0; j < 4; ++j) {
        int row = m0 + wr * 128 + mi * 16 + l4 * 4 + j;
        size_t idx = (size_t)row * N + col;
        float g = acc[mi][ni][j];
        if constexpr (EPI == 2) {
          Cb[idx] = f2bf(g);
        } else {
          float gv = bf2f(Cb[idx]);
          float sg = gv / (1.f + __expf(-gv));
          Cb[idx] = f2bf(sg * g);
        }
      }
    }
}

// ---------------------------------------------------------------------------
// 128x128 2-phase dbuf GEMM with granule-XOR swizzle (QKVZ / Wo / Wd).
// EPI 0: f32. EPI 1: f32 + residual. EPI 2: bf16.
// ---------------------------------------------------------------------------
template <int EPI>
__global__ __launch_bounds__(256) void k_gemm_bt(
    const unsigned short* __restrict__ A, const unsigned short* __restrict__ B,
    float* __restrict__ Cf, unsigned short* __restrict__ Cb,
    const float* __restrict__ res,
    int M, int N, int K) {
  __shared__ unsigned short As[2][128 * 32];
  __shared__ unsigned short Bs[2][128 * 32];

  const int t = threadIdx.x, lane = t & 63, w = t >> 6;
  const int wr = w >> 1, wc = w & 1;
  const int l15 = lane & 15, l4 = lane >> 4;
  const int nbx = gridDim.x;
  const int nwg = nbx * gridDim.y;
  const int bid = blockIdx.y * nbx + blockIdx.x;
  const int sw = (bid & 7) * (nwg >> 3) + (bid >> 3);
  const int tpg = 8 * nbx;
  const int mi = (sw / tpg) * 8 + (sw & 7);
  const int ni = (sw % tpg) >> 3;
  const int m0 = mi * 128, n0 = ni * 128;

  f32x4 acc[4][4] = {};

  const int srow = lane >> 2;
  const int scol = (((lane & 3) ^ (srow & 3))) * 8;
  const int rg = (l4 ^ (l15 & 3)) * 8;

  auto stage = [&](int kk, int sel) {
#pragma unroll
    for (int r = 0; r < 2; ++r) {
      int row = 16 * w + srow + 64 * r;
      gload16(A + (size_t)(m0 + row) * K + kk + scol, (void*)&As[sel][w * 512 + r * 2048]);
      gload16(B + (size_t)(n0 + row) * K + kk + scol, (void*)&Bs[sel][w * 512 + r * 2048]);
    }
  };

  stage(0, 0);
  __syncthreads();

  const int nk = K >> 5;
  for (int tk = 0; tk < nk; ++tk) {
    const int cur = tk & 1;
    if (tk + 1 < nk) stage((tk + 1) << 5, cur ^ 1);

    s16x8 af[4], bf_[4];
#pragma unroll
    for (int i = 0; i < 4; ++i) {
      af[i]  = *(const s16x8*)&As[cur][(wr * 64 + i * 16 + l15) * 32 + rg];
      bf_[i] = *(const s16x8*)&Bs[cur][(wc * 64 + i * 16 + l15) * 32 + rg];
    }
#pragma unroll
    for (int mi2 = 0; mi2 < 4; ++mi2)
#pragma unroll
      for (int ni2 = 0; ni2 < 4; ++ni2)
        acc[mi2][ni2] = MFMA_BF16(af[mi2], bf_[ni2], acc[mi2][ni2], 0, 0, 0);
    __syncthreads();
  }

  const int er = (lane >> 4) * 4;
  const int ec = lane & 15;
#pragma unroll
  for (int mi2 = 0; mi2 < 4; ++mi2)
#pragma unroll
    for (int ni2 = 0; ni2 < 4; ++ni2) {
      int col = n0 + wc * 64 + ni2 * 16 + ec;
#pragma unroll
      for (int j = 0; j < 4; ++j) {
        int row = m0 + wr * 64 + mi2 * 16 + er + j;
        size_t idx = (size_t)row * N + col;
        float g = acc[mi2][ni2][j];
        if constexpr (EPI == 0) {
          Cf[idx] = g;
        } else if constexpr (EPI == 1) {
          Cf[idx] = g + res[idx];
        } else if constexpr (EPI == 2) {
          Cb[idx] = f2bf(g);
        } else {
          float gv = bf2f(Cb[idx]);
          float sg = gv / (1.f + __expf(-gv));
          Cb[idx] = f2bf(sg * g);
        }
      }
    }
}

// ---------------------------------------------------------------------------
// Causal GQA attention, bf16 MFMA flash.
// ---------------------------------------------------------------------------
__global__ __launch_bounds__(256) void k_attn_mfma(
    const unsigned short* __restrict__ Qb,
    const unsigned short* __restrict__ Kb,
    const unsigned short* __restrict__ Vt,
    const unsigned short* __restrict__ Zb,
    unsigned short* __restrict__ AO) {
  __shared__ unsigned short Qs[64 * 128];
  __shared__ unsigned short Ks[64 * 128];
  __shared__ unsigned short Vts[128 * 64];
  __shared__ unsigned short Ps[4][16 * 64];

  const int t = threadIdx.x, lane = t & 63, w = t >> 6;
  const int l15 = lane & 15, l4 = lane >> 4;
  const int qt = (int)gridDim.x - 1 - (int)blockIdx.x;
  const int qs0 = qt * 64;
  const int h = blockIdx.y, b = blockIdx.z;
  const int kv = h >> 2;

  {
    const unsigned short* qb = Qb + (size_t)(b * 1024 + qs0) * 2048 + h * 128;
#pragma unroll
    for (int r = 0; r < 4; ++r) {
      int row = r * 16 + w * 4 + (lane >> 4);
      int cp = lane & 15;
      int c = (cp & 8) | ((cp & 7) ^ (row & 7));
      gload16(qb + (size_t)row * 2048 + c * 8, (void*)&Qs[(r * 256 + w * 64) * 8]);
    }
  }

  auto stageKV = [&](int j0) {
    const unsigned short* kb = Kb + (size_t)(b * 1024 + j0) * 512 + kv * 128;
#pragma unroll
    for (int r = 0; r < 4; ++r) {
      int row = r * 16 + w * 4 + (lane >> 4);
      int cp = lane & 15;
      int c = (cp & 8) | ((cp & 7) ^ (row & 7));
      gload16(kb + (size_t)row * 512 + c * 8, (void*)&Ks[(r * 256 + w * 64) * 8]);
    }
    const unsigned short* vb = Vt + (size_t)(b * 4 + kv) * 131072 + j0;
#pragma unroll
    for (int r = 0; r < 4; ++r) {
      int row = r * 32 + w * 8 + (lane >> 3);
      int cp = lane & 7;
      int c = cp ^ (row & 7);
      gload16(vb + (size_t)row * 1024 + c * 8, (void*)&Vts[(r * 256 + w * 64) * 8]);
    }
  };

  stageKV(0);
  __syncthreads();

  s16x8 qf[4];
#pragma unroll
  for (int ks = 0; ks < 4; ++ks) {
    int R = w * 16 + l15;
    int c = ks * 4 + l4;
    int cp = (c & 8) | ((c & 7) ^ (R & 7));
    qf[ks] = *(const s16x8*)&Qs[R * 128 + cp * 8];
  }

  f32x4 O[8] = {};
  f32x4 mrow = {-1e30f, -1e30f, -1e30f, -1e30f};
  f32x4 lrow = {0.f, 0.f, 0.f, 0.f};
  const float scale = 0.088388347648318447f;

  for (int tile = 0; tile <= qt; ++tile) {
    f32x4 sc[4] = {};
#pragma unroll
    for (int ks = 0; ks < 4; ++ks) {
#pragma unroll
      for (int kt = 0; kt < 4; ++kt) {
        int R = kt * 16 + l15;
        int c = ks * 4 + l4;
        int cp = (c & 8) | ((c & 7) ^ (R & 7));
        s16x8 kf = *(const s16x8*)&Ks[R * 128 + cp * 8];
        sc[kt] = MFMA_BF16(qf[ks], kf, sc[kt], 0, 0, 0);
      }
    }
    const bool diag = (tile == qt);
#pragma unroll
    for (int kt = 0; kt < 4; ++kt) {
      int key = kt * 16 + l15;
#pragma unroll
      for (int j = 0; j < 4; ++j) {
        float s = sc[kt][j] * scale;
        if (diag && key > (w * 16 + l4 * 4 + j)) s = -1e30f;
        sc[kt][j] = s;
      }
    }
    f32x4 mt;
#pragma unroll
    for (int j = 0; j < 4; ++j)
      mt[j] = fmaxf(fmaxf(sc[0][j], sc[1][j]), fmaxf(sc[2][j], sc[3][j]));
#pragma unroll
    for (int msk = 1; msk < 16; msk <<= 1)
#pragma unroll
      for (int j = 0; j < 4; ++j) mt[j] = fmaxf(mt[j], __shfl_xor(mt[j], msk));
    f32x4 mnew, rs;
#pragma unroll
    for (int j = 0; j < 4; ++j) {
      mnew[j] = fmaxf(mrow[j], mt[j]);
      rs[j] = __expf(mrow[j] - mnew[j]);
    }
    f32x4 psum = {0.f, 0.f, 0.f, 0.f};
    unsigned short* pw = &Ps[w][0];
#pragma unroll
    for (int kt = 0; kt < 4; ++kt) {
      int kg = kt * 2 + (l15 >> 3), ke = l15 & 7;
#pragma unroll
      for (int j = 0; j < 4; ++j) {
        float p = __expf(sc[kt][j] - mnew[j]);
        psum[j] += p;
        int q = l4 * 4 + j;
        pw[q * 64 + ((kg ^ (q & 7)) * 8) + ke] = f2bf(p);
      }
    }
#pragma unroll
    for (int msk = 1; msk < 16; msk <<= 1)
#pragma unroll
      for (int j = 0; j < 4; ++j) psum[j] += __shfl_xor(psum[j], msk);
    mrow = mnew;
#pragma unroll
    for (int j = 0; j < 4; ++j) lrow[j] = lrow[j] * rs[j] + psum[j];
#pragma unroll
    for (int dt = 0; dt < 8; ++dt) O[dt] *= rs;
#pragma unroll
    for (int js = 0; js < 2; ++js) {
      int cpp = (js * 4 + l4) ^ (l15 & 7);
      s16x8 pf = *(const s16x8*)&Ps[w][l15 * 64 + cpp * 8];
#pragma unroll
      for (int dt = 0; dt < 8; ++dt) {
        int D = dt * 16 + l15;
        s16x8 vf = *(const s16x8*)&Vts[D * 64 + cpp * 8];
        O[dt] = MFMA_BF16(pf, vf, O[dt], 0, 0, 0);
      }
    }
    __syncthreads();
    if (tile < qt) stageKV((tile + 1) * 64);
    __syncthreads();
  }

  f32x4 linv;
#pragma unroll
  for (int j = 0; j < 4; ++j) linv[j] = 1.f / lrow[j];
  const int tok0 = b * 1024 + qs0 + w * 16 + l4 * 4;
#pragma unroll
  for (int dt = 0; dt < 8; ++dt) {
    int d = dt * 16 + l15;
#pragma unroll
    for (int j = 0; j < 4; ++j) {
      size_t zidx = (size_t)(tok0 + j) * 5120 + h * 128 + d;
      size_t aidx = (size_t)(tok0 + j) * 2048 + h * 128 + d;
      float z = bf2f(Zb[zidx]);
      float o = O[dt][j] * linv[j];
      AO[aidx] = f2bf(o / (1.f + __expf(-z)));
    }
  }
}

// ---------------------------------------------------------------------------
// launcher
// ---------------------------------------------------------------------------
extern "C" void kernel_launch(void* const* d_in, const int* in_sizes, int n_in,
                              void* d_out, int out_size, void* d_ws, size_t ws_size,
                              hipStream_t stream) {
  const float* x       = (const float*)d_in[0];
  const float* in_ln   = (const float*)d_in[1];
  const float* Wq      = (const float*)d_in[2];
  const float* Wk      = (const float*)d_in[3];
  const float* Wv      = (const float*)d_in[4];
  const float* Wz      = (const float*)d_in[5];
  const float* Wo      = (const float*)d_in[6];
  const float* qn_w    = (const float*)d_in[7];
  const float* kn_w    = (const float*)d_in[8];
  const float* post_ln = (const float*)d_in[9];
  const float* Wg      = (const float*)d_in[10];
  const float* Wu      = (const float*)d_in[11];
  const float* Wd      = (const float*)d_in[12];

  const int T = 4096;

  char* ws = (char*)d_ws;
  size_t off = 0;
  auto alloc = [&](size_t bytes) -> void* {
    off = (off + 255) & ~(size_t)255;
    void* p = ws + off;
    off += bytes;
    return p;
  };

  unsigned short* Wqkvz_b = (unsigned short*)alloc((size_t)5120 * 2048 * 2);
  unsigned short* Wo_b = (unsigned short*)alloc((size_t)2048 * 2048 * 2);
  unsigned short* Wg_b = (unsigned short*)alloc((size_t)8192 * 2048 * 2);
  unsigned short* Wu_b = (unsigned short*)alloc((size_t)8192 * 2048 * 2);
  unsigned short* Wd_b = (unsigned short*)alloc((size_t)2048 * 8192 * 2);

  char* R = (char*)alloc((size_t)64 * 1024 * 1024);
  unsigned short* qkvz_bf = (unsigned short*)R;
  unsigned short* h_bf    = (unsigned short*)(R + (size_t)40 * 1024 * 1024);
  unsigned short* gu_bf   = (unsigned short*)R;
  unsigned short* ao_bf   = h_bf;

  float* x2 = (float*)alloc((size_t)T * 2048 * 4);
  char* x2c = (char*)x2;
  unsigned short* vt_bf = (unsigned short*)(x2c);
  unsigned short* k_bf  = (unsigned short*)(x2c + 4194304);
  unsigned short* q_bf  = (unsigned short*)(x2c + 8388608);

  unsigned short* h2_bf = (unsigned short*)alloc((size_t)T * 2048 * 2);
  float* cosT = (float*)alloc((size_t)1024 * 64 * 4);
  float* sinT = (float*)alloc((size_t)1024 * 64 * 4);

  auto cvt = [&](const float* s, unsigned short* d, size_t n) {
    int n4 = (int)(n / 4);
    int blocks = (n4 + 255) / 256;
    if (blocks > 2048) blocks = 2048;
    k_f32_to_bf16<<<blocks, 256, 0, stream>>>(s, d, n4);
  };
  cvt(Wq, Wqkvz_b, (size_t)2048 * 2048);
  cvt(Wk, Wqkvz_b + (size_t)2048 * 2048, (size_t)512 * 2048);
  cvt(Wv, Wqkvz_b + (size_t)2560 * 2048, (size_t)512 * 2048);
  cvt(Wz, Wqkvz_b + (size_t)3072 * 2048, (size_t)2048 * 2048);
  cvt(Wo, Wo_b, (size_t)2048 * 2048);
  cvt(Wg, Wg_b, (size_t)8192 * 2048);
  cvt(Wu, Wu_b, (size_t)8192 * 2048);
  cvt(Wd, Wd_b, (size_t)2048 * 8192);

  k_rope_table<<<256, 256, 0, stream>>>(cosT, sinT);

  // h = rmsnorm(x, in_ln)
  k_rmsnorm<<<T, 256, 0, stream>>>(x, in_ln, h_bf);

  // fused QKVZ projection: [4096][5120] bf16 (128² dbuf)
  k_gemm_bt<2><<<dim3(40, 32), 256, 0, stream>>>(h_bf, Wqkvz_b, nullptr, qkvz_bf, nullptr, T, 5120, 2048);

  // per-head q/k RMSNorm + RoPE -> bf16
  k_qknorm_rope<<<20480, 256, 0, stream>>>(qkvz_bf, q_bf, k_bf, qn_w, kn_w, cosT, sinT);

  // V -> V^T bf16 per (b,kv)
  k_transpose_v<<<dim3(16, 4, 4), 256, 0, stream>>>(qkvz_bf, vt_bf);

  // causal GQA attention (MFMA) + sigmoid(z) gate -> ao_bf
  k_attn_mfma<<<dim3(16, 16, 4), 256, 0, stream>>>(q_bf, k_bf, vt_bf, qkvz_bf + 3072, ao_bf);

  // x2 = x + ao @ Wo^T
  k_gemm_bt<1><<<dim3(16, 32), 256, 0, stream>>>(ao_bf, Wo_b, x2, nullptr, x, T, 2048, 2048);

  // h2 = rmsnorm(x2, post_ln)
  k_rmsnorm<<<T, 256, 0, stream>>>(x2, post_ln, h2_bf);

  // gu = h2 @ Wg^T  (bf16, 4-phase 256²)
  k_gemm256<2><<<dim3(32, 16), 512, 0, stream>>>(h2_bf, Wg_b, gu_bf, T, 8192, 2048);

  // gu = silu(gu) * (h2 @ Wu^T)  (in place, 4-phase 256²)
  k_gemm256<4><<<dim3(32, 16), 512, 0, stream>>>(h2_bf, Wu_b, gu_bf, T, 8192, 2048);

  // out = x2 + gu @ Wd^T  (128² dbuf)
  k_gemm_bt<1><<<dim3(16, 32), 256, 0, stream>>>(gu_bf, Wd_b, (float*)d_out, nullptr, x2, T, 2048, 8192);
}

// Round 16
// 833.251 us; speedup vs baseline: 1.0337x; 1.0103x over previous
//
#include <hip/hip_runtime.h>

// ---------------------------------------------------------------------------
// DecoderLayer on MI355X — converged configuration:
//  - k_cvt_all: single fused f32->bf16 weight conversion (8 segments).
//  - k_gemm256 (4-phase, 256x256, BK=64, XOR-swizzle, setprio): Wg, Wu.
//  - k_gemm_bt (128x128, BK=32, dbuf, supertile raster): QKVZ, Wo, Wd.
//  - k_attn_mfma: bf16 MFMA flash attention with fused sigmoid(z) gate.
// ---------------------------------------------------------------------------

typedef __attribute__((ext_vector_type(4))) float  f32x4;
typedef __attribute__((ext_vector_type(8))) short  s16x8;
typedef __attribute__((ext_vector_type(4))) unsigned short u16x4;

#define DEVI static __device__ __forceinline__

DEVI unsigned short f2bf(float f) {
  union { float f; unsigned u; } a; a.f = f;
  unsigned r = a.u + 0x7FFFu + ((a.u >> 16) & 1u);
  return (unsigned short)(r >> 16);
}
DEVI float bf2f(unsigned short u) {
  union { unsigned u; float f; } a; a.u = (unsigned)u << 16; return a.f;
}

DEVI void gload16(const void* g, void* l) {
  __builtin_amdgcn_global_load_lds(
      (const __attribute__((address_space(1))) unsigned int*)(unsigned long long)g,
      (__attribute__((address_space(3))) unsigned int*)(unsigned int)(unsigned long long)l,
      16, 0, 0);
}

#define MFMA_BF16 __builtin_amdgcn_mfma_f32_16x16x32_bf16
#define WAITV8()  asm volatile("s_waitcnt vmcnt(8)" ::: "memory")
#define WAITV0()  asm volatile("s_waitcnt vmcnt(0)" ::: "memory")
#define PIN()     __builtin_amdgcn_sched_barrier(0)
#define LGKM0()   do { asm volatile("s_waitcnt lgkmcnt(0)" ::: "memory"); \
                       __builtin_amdgcn_sched_barrier(0); } while (0)

// ---------------------------------------------------------------------------
// Fused weight conversion: 8 segments, blockIdx.y selects segment.
// ---------------------------------------------------------------------------
struct Cvt8 {
  const float* src[8];
  unsigned short* dst[8];
  int n4[8];
};

__global__ __launch_bounds__(256) void k_cvt_all(Cvt8 c) {
  const int seg = blockIdx.y;
  const f32x4* s = (const f32x4*)c.src[seg];
  u16x4* d = (u16x4*)c.dst[seg];
  const int n = c.n4[seg];
  const int stride = gridDim.x * blockDim.x;
  for (int i = blockIdx.x * blockDim.x + threadIdx.x; i < n; i += stride) {
    f32x4 v = s[i];
    u16x4 o;
    o.x = f2bf(v.x); o.y = f2bf(v.y); o.z = f2bf(v.z); o.w = f2bf(v.w);
    d[i] = o;
  }
}

// ---------------------------------------------------------------------------
__global__ __launch_bounds__(256) void k_rmsnorm(const float* __restrict__ x,
                                                 const float* __restrict__ w,
                                                 unsigned short* __restrict__ out) {
  const int row = blockIdx.x, t = threadIdx.x;
  const f32x4* xr = (const f32x4*)(x + (size_t)row * 2048);
  f32x4 a = xr[t * 2], b = xr[t * 2 + 1];
  float ss = a.x*a.x + a.y*a.y + a.z*a.z + a.w*a.w
           + b.x*b.x + b.y*b.y + b.z*b.z + b.w*b.w;
#pragma unroll
  for (int m = 32; m; m >>= 1) ss += __shfl_xor(ss, m);
  __shared__ float sred[4];
  if ((t & 63) == 0) sred[t >> 6] = ss;
  __syncthreads();
  float tot = sred[0] + sred[1] + sred[2] + sred[3];
  float r = rsqrtf(tot * (1.0f / 2048.0f) + 1e-6f);
  const f32x4* wr = (const f32x4*)w;
  f32x4 w1 = wr[t * 2], w2 = wr[t * 2 + 1];
  u16x4 o1, o2;
  o1.x = f2bf(a.x * r * (1.f + w1.x)); o1.y = f2bf(a.y * r * (1.f + w1.y));
  o1.z = f2bf(a.z * r * (1.f + w1.z)); o1.w = f2bf(a.w * r * (1.f + w1.w));
  o2.x = f2bf(b.x * r * (1.f + w2.x)); o2.y = f2bf(b.y * r * (1.f + w2.y));
  o2.z = f2bf(b.z * r * (1.f + w2.z)); o2.w = f2bf(b.w * r * (1.f + w2.w));
  u16x4* od = (u16x4*)(out + (size_t)row * 2048);
  od[t * 2] = o1; od[t * 2 + 1] = o2;
}

// ---------------------------------------------------------------------------
__global__ void k_rope_table(float* __restrict__ cosT, float* __restrict__ sinT) {
  int i = blockIdx.x * blockDim.x + threadIdx.x;
  int tpos = i >> 6, f = i & 63;
  double inv = exp(-0.14391156831212787 * (double)f);
  float ang = (float)tpos * (float)inv;
  cosT[i] = cosf(ang);
  sinT[i] = sinf(ang);
}

// ---------------------------------------------------------------------------
__global__ __launch_bounds__(256) void k_qknorm_rope(
    const unsigned short* __restrict__ QKVZ,
    unsigned short* __restrict__ Qo, unsigned short* __restrict__ Ko,
    const float* __restrict__ qw, const float* __restrict__ kw,
    const float* __restrict__ cosT, const float* __restrict__ sinT) {
  int gid = blockIdx.x * 4 + (threadIdx.x >> 6);
  int lane = threadIdx.x & 63;
  int tok = gid / 20, hh = gid % 20;
  const unsigned short* p; const float* w; unsigned short* o;
  if (hh < 16) { p = QKVZ + (size_t)tok * 5120 + hh * 128; w = qw;
                 o = Qo + (size_t)tok * 2048 + hh * 128; }
  else         { p = QKVZ + (size_t)tok * 5120 + 2048 + (hh - 16) * 128; w = kw;
                 o = Ko + (size_t)tok * 512 + (hh - 16) * 128; }
  float x1 = bf2f(p[lane]), x2 = bf2f(p[lane + 64]);
  float ss = x1 * x1 + x2 * x2;
#pragma unroll
  for (int m = 1; m < 64; m <<= 1) ss += __shfl_xor(ss, m);
  float r = rsqrtf(ss * (1.0f / 128.0f) + 1e-6f);
  float n1 = x1 * r * (1.f + w[lane]);
  float n2 = x2 * r * (1.f + w[lane + 64]);
  int s = tok & 1023;
  float c = cosT[s * 64 + lane], sn = sinT[s * 64 + lane];
  o[lane]      = f2bf(n1 * c - n2 * sn);
  o[lane + 64] = f2bf(n2 * c + n1 * sn);
}

// ---------------------------------------------------------------------------
__global__ __launch_bounds__(256) void k_transpose_v(const unsigned short* __restrict__ QKVZ,
                                                     unsigned short* __restrict__ Vt) {
  __shared__ unsigned short Vl[128 * 66];
  const int t = threadIdx.x;
  const int key0 = blockIdx.x * 64, kvh = blockIdx.y, b = blockIdx.z;
#pragma unroll
  for (int i = 0; i < 4; ++i) {
    int g = i * 256 + t;
    int key = g >> 4, dc = (g & 15) * 8;
    s16x8 v = *(const s16x8*)&QKVZ[(size_t)(b * 1024 + key0 + key) * 5120 + 2560 + kvh * 128 + dc];
#pragma unroll
    for (int j = 0; j < 8; ++j) Vl[(dc + j) * 66 + key] = (unsigned short)v[j];
  }
  __syncthreads();
#pragma unroll
  for (int i = 0; i < 8; ++i) {
    int g = i * 256 + t;
    int d = g >> 4, kc = g & 15;
    u16x4 o;
#pragma unroll
    for (int j = 0; j < 4; ++j) o[j] = Vl[d * 66 + kc * 4 + j];
    *(u16x4*)&Vt[((size_t)(b * 4 + kvh) * 128 + d) * 1024 + key0 + kc * 4] = o;
  }
}

// ---------------------------------------------------------------------------
// 256x256 GEMM, BK=64, 8 waves, 4-phase/K-tile. Wg + Wu.
// EPI 2: store bf16.  EPI 4: in-place bf16( silu(Cb[idx]) * acc ).
// ---------------------------------------------------------------------------
template <int EPI>
__global__ __launch_bounds__(512) void k_gemm256(
    const unsigned short* __restrict__ A, const unsigned short* __restrict__ B,
    unsigned short* __restrict__ Cb, int M, int N, int K) {
  __shared__ unsigned short As[2][256][64];
  __shared__ unsigned short Bs[2][256][64];

  const int t = threadIdx.x, lane = t & 63, w = t >> 6;
  const int wr = w >> 2, wc = w & 3;
  const int l15 = lane & 15, l4 = lane >> 4;
  const int xg = l15 & 7;
  const int hb = wc >> 1, cl = wc & 1;

  const int nbx = gridDim.x;
  const int nwg = nbx * gridDim.y;
  const int bid = blockIdx.y * nbx + blockIdx.x;
  const int sw = (bid & 7) * (nwg >> 3) + (bid >> 3);
  const int tpg = 8 * nbx;
  const int mi_ = (sw / tpg) * 8 + (sw & 7);
  const int ni_ = (sw % tpg) >> 3;
  const int m0 = mi_ * 256, n0 = ni_ * 256;

  const int NT = K >> 6;

  auto stageA = [&](int tt, int pm) {
    int dd = tt & 1;
#pragma unroll
    for (int c = 0; c < 2; ++c) {
      int r0 = wr * 128 + pm * 64 + wc * 16 + c * 8;
      int r = r0 + (lane >> 3);
      int gs = (lane & 7) ^ (r & 7);
      gload16(A + (size_t)(m0 + r) * K + tt * 64 + gs * 8, (void*)&As[dd][r0][0]);
    }
  };
  auto stageB = [&](int tt, int pn) {
    int dd = tt & 1;
#pragma unroll
    for (int c = 0; c < 2; ++c) {
      int r0 = hb * 128 + cl * 64 + pn * 32 + wr * 16 + c * 8;
      int r = r0 + (lane >> 3);
      int gs = (lane & 7) ^ (r & 7);
      gload16(B + (size_t)(n0 + r) * K + tt * 64 + gs * 8, (void*)&Bs[dd][r0][0]);
    }
  };

  stageA(0, 0); stageB(0, 0); stageB(0, 1); stageA(0, 1);
  stageA(1, 0); stageB(1, 0); stageB(1, 1); stageA(1, 1);

  f32x4 acc[8][4] = {};

  WAITV8();
  __builtin_amdgcn_s_barrier();

  for (int u = 0; u < NT; ++u) {
    const int cur = u & 1;
    const bool deep = (u + 2 < NT);
    s16x8 afL[4][2], afH[4][2], bf0[2][2], bf1[2][2];

#pragma unroll
    for (int i = 0; i < 4; ++i) {
      int row = wr * 128 + i * 16 + l15;
      afL[i][0] = *(const s16x8*)&As[cur][row][(l4 ^ xg) * 8];
      afL[i][1] = *(const s16x8*)&As[cur][row][((l4 ^ xg) ^ 4) * 8];
    }
#pragma unroll
    for (int n = 0; n < 2; ++n) {
      int row = wc * 64 + n * 16 + l15;
      bf0[n][0] = *(const s16x8*)&Bs[cur][row][(l4 ^ xg) * 8];
      bf0[n][1] = *(const s16x8*)&Bs[cur][row][((l4 ^ xg) ^ 4) * 8];
    }
    PIN();
    __builtin_amdgcn_s_barrier();
    LGKM0();
    __builtin_amdgcn_s_setprio(1);
#pragma unroll
    for (int i = 0; i < 4; ++i)
#pragma unroll
      for (int n = 0; n < 2; ++n) {
        acc[i][n] = MFMA_BF16(afL[i][0], bf0[n][0], acc[i][n], 0, 0, 0);
        acc[i][n] = MFMA_BF16(afL[i][1], bf0[n][1], acc[i][n], 0, 0, 0);
      }
    __builtin_amdgcn_s_setprio(0);
    __builtin_amdgcn_s_barrier();

#pragma unroll
    for (int n = 0; n < 2; ++n) {
      int row = wc * 64 + (2 + n) * 16 + l15;
      bf1[n][0] = *(const s16x8*)&Bs[cur][row][(l4 ^ xg) * 8];
      bf1[n][1] = *(const s16x8*)&Bs[cur][row][((l4 ^ xg) ^ 4) * 8];
    }
    if (deep) stageA(u + 2, 0);
    PIN();
    __builtin_amdgcn_s_barrier();
    LGKM0();
    __builtin_amdgcn_s_setprio(1);
#pragma unroll
    for (int i = 0; i < 4; ++i)
#pragma unroll
      for (int n = 0; n < 2; ++n) {
        acc[i][2 + n] = MFMA_BF16(afL[i][0], bf1[n][0], acc[i][2 + n], 0, 0, 0);
        acc[i][2 + n] = MFMA_BF16(afL[i][1], bf1[n][1], acc[i][2 + n], 0, 0, 0);
      }
    __builtin_amdgcn_s_setprio(0);
    __builtin_amdgcn_s_barrier();

#pragma unroll
    for (int i = 0; i < 4; ++i) {
      int row = wr * 128 + 64 + i * 16 + l15;
      afH[i][0] = *(const s16x8*)&As[cur][row][(l4 ^ xg) * 8];
      afH[i][1] = *(const s16x8*)&As[cur][row][((l4 ^ xg) ^ 4) * 8];
    }
    if (deep) { stageB(u + 2, 0); stageB(u + 2, 1); }
    PIN();
    __builtin_amdgcn_s_barrier();
    LGKM0();
    __builtin_amdgcn_s_setprio(1);
#pragma unroll
    for (int i = 0; i < 4; ++i)
#pragma unroll
      for (int n = 0; n < 2; ++n) {
        acc[4 + i][2 + n] = MFMA_BF16(afH[i][0], bf1[n][0], acc[4 + i][2 + n], 0, 0, 0);
        acc[4 + i][2 + n] = MFMA_BF16(afH[i][1], bf1[n][1], acc[4 + i][2 + n], 0, 0, 0);
      }
    __builtin_amdgcn_s_setprio(0);
    __builtin_amdgcn_s_barrier();

    if (deep) stageA(u + 2, 1);
    if (deep) WAITV8(); else WAITV0();
    PIN();
    __builtin_amdgcn_s_barrier();
    __builtin_amdgcn_s_setprio(1);
#pragma unroll
    for (int i = 0; i < 4; ++i)
#pragma unroll
      for (int n = 0; n < 2; ++n) {
        acc[4 + i][n] = MFMA_BF16(afH[i][0], bf0[n][0], acc[4 + i][n], 0, 0, 0);
        acc[4 + i][n] = MFMA_BF16(afH[i][1], bf0[n][1], acc[4 + i][n], 0, 0, 0);
      }
    __builtin_amdgcn_s_setprio(0);
    __builtin_amdgcn_s_barrier();
  }

#pragma unroll
  for (int mi = 0; mi < 8; ++mi)
#pragma unroll
    for (int ni = 0; ni < 4; ++ni) {
      int col = n0 + wc * 64 + ni * 16 + l15;
#pragma unroll
      for (int j = 0; j < 4; ++j) {
        int row = m0 + wr * 128 + mi * 16 + l4 * 4 + j;
        size_t idx = (size_t)row * N + col;
        float g = acc[mi][ni][j];
        if constexpr (EPI == 2) {
          Cb[idx] = f2bf(g);
        } else {
          float gv = bf2f(Cb[idx]);
          float sg = gv / (1.f + __expf(-gv));
          Cb[idx] = f2bf(sg * g);
        }
      }
    }
}

// ---------------------------------------------------------------------------
// 128x128 2-phase dbuf GEMM with granule-XOR swizzle (QKVZ / Wo / Wd).
// EPI 0: f32. EPI 1: f32 + residual. EPI 2: bf16.
// ---------------------------------------------------------------------------
template <int EPI>
__global__ __launch_bounds__(256) void k_gemm_bt(
    const unsigned short* __restrict__ A, const unsigned short* __restrict__ B,
    float* __restrict__ Cf, unsigned short* __restrict__ Cb,
    const float* __restrict__ res,
    int M, int N, int K) {
  __shared__ unsigned short As[2][128 * 32];
  __shared__ unsigned short Bs[2][128 * 32];

  const int t = threadIdx.x, lane = t & 63, w = t >> 6;
  const int wr = w >> 1, wc = w & 1;
  const int l15 = lane & 15, l4 = lane >> 4;
  const int nbx = gridDim.x;
  const int nwg = nbx * gridDim.y;
  const int bid = blockIdx.y * nbx + blockIdx.x;
  const int sw = (bid & 7) * (nwg >> 3) + (bid >> 3);
  const int tpg = 8 * nbx;
  const int mi = (sw / tpg) * 8 + (sw & 7);
  const int ni = (sw % tpg) >> 3;
  const int m0 = mi * 128, n0 = ni * 128;

  f32x4 acc[4][4] = {};

  const int srow = lane >> 2;
  const int scol = (((lane & 3) ^ (srow & 3))) * 8;
  const int rg = (l4 ^ (l15 & 3)) * 8;

  auto stage = [&](int kk, int sel) {
#pragma unroll
    for (int r = 0; r < 2; ++r) {
      int row = 16 * w + srow + 64 * r;
      gload16(A + (size_t)(m0 + row) * K + kk + scol, (void*)&As[sel][w * 512 + r * 2048]);
      gload16(B + (size_t)(n0 + row) * K + kk + scol, (void*)&Bs[sel][w * 512 + r * 2048]);
    }
  };

  stage(0, 0);
  __syncthreads();

  const int nk = K >> 5;
  for (int tk = 0; tk < nk; ++tk) {
    const int cur = tk & 1;
    if (tk + 1 < nk) stage((tk + 1) << 5, cur ^ 1);

    s16x8 af[4], bf_[4];
#pragma unroll
    for (int i = 0; i < 4; ++i) {
      af[i]  = *(const s16x8*)&As[cur][(wr * 64 + i * 16 + l15) * 32 + rg];
      bf_[i] = *(const s16x8*)&Bs[cur][(wc * 64 + i * 16 + l15) * 32 + rg];
    }
#pragma unroll
    for (int mi2 = 0; mi2 < 4; ++mi2)
#pragma unroll
      for (int ni2 = 0; ni2 < 4; ++ni2)
        acc[mi2][ni2] = MFMA_BF16(af[mi2], bf_[ni2], acc[mi2][ni2], 0, 0, 0);
    __syncthreads();
  }

  const int er = (lane >> 4) * 4;
  const int ec = lane & 15;
#pragma unroll
  for (int mi2 = 0; mi2 < 4; ++mi2)
#pragma unroll
    for (int ni2 = 0; ni2 < 4; ++ni2) {
      int col = n0 + wc * 64 + ni2 * 16 + ec;
#pragma unroll
      for (int j = 0; j < 4; ++j) {
        int row = m0 + wr * 64 + mi2 * 16 + er + j;
        size_t idx = (size_t)row * N + col;
        float g = acc[mi2][ni2][j];
        if constexpr (EPI == 0) {
          Cf[idx] = g;
        } else if constexpr (EPI == 1) {
          Cf[idx] = g + res[idx];
        } else if constexpr (EPI == 2) {
          Cb[idx] = f2bf(g);
        } else {
          float gv = bf2f(Cb[idx]);
          float sg = gv / (1.f + __expf(-gv));
          Cb[idx] = f2bf(sg * g);
        }
      }
    }
}

// ---------------------------------------------------------------------------
// Causal GQA attention, bf16 MFMA flash.
// ---------------------------------------------------------------------------
__global__ __launch_bounds__(256) void k_attn_mfma(
    const unsigned short* __restrict__ Qb,
    const unsigned short* __restrict__ Kb,
    const unsigned short* __restrict__ Vt,
    const unsigned short* __restrict__ Zb,
    unsigned short* __restrict__ AO) {
  __shared__ unsigned short Qs[64 * 128];
  __shared__ unsigned short Ks[64 * 128];
  __shared__ unsigned short Vts[128 * 64];
  __shared__ unsigned short Ps[4][16 * 64];

  const int t = threadIdx.x, lane = t & 63, w = t >> 6;
  const int l15 = lane & 15, l4 = lane >> 4;
  const int qt = (int)gridDim.x - 1 - (int)blockIdx.x;
  const int qs0 = qt * 64;
  const int h = blockIdx.y, b = blockIdx.z;
  const int kv = h >> 2;

  {
    const unsigned short* qb = Qb + (size_t)(b * 1024 + qs0) * 2048 + h * 128;
#pragma unroll
    for (int r = 0; r < 4; ++r) {
      int row = r * 16 + w * 4 + (lane >> 4);
      int cp = lane & 15;
      int c = (cp & 8) | ((cp & 7) ^ (row & 7));
      gload16(qb + (size_t)row * 2048 + c * 8, (void*)&Qs[(r * 256 + w * 64) * 8]);
    }
  }

  auto stageKV = [&](int j0) {
    const unsigned short* kb = Kb + (size_t)(b * 1024 + j0) * 512 + kv * 128;
#pragma unroll
    for (int r = 0; r < 4; ++r) {
      int row = r * 16 + w * 4 + (lane >> 4);
      int cp = lane & 15;
      int c = (cp & 8) | ((cp & 7) ^ (row & 7));
      gload16(kb + (size_t)row * 512 + c * 8, (void*)&Ks[(r * 256 + w * 64) * 8]);
    }
    const unsigned short* vb = Vt + (size_t)(b * 4 + kv) * 131072 + j0;
#pragma unroll
    for (int r = 0; r < 4; ++r) {
      int row = r * 32 + w * 8 + (lane >> 3);
      int cp = lane & 7;
      int c = cp ^ (row & 7);
      gload16(vb + (size_t)row * 1024 + c * 8, (void*)&Vts[(r * 256 + w * 64) * 8]);
    }
  };

  stageKV(0);
  __syncthreads();

  s16x8 qf[4];
#pragma unroll
  for (int ks = 0; ks < 4; ++ks) {
    int R = w * 16 + l15;
    int c = ks * 4 + l4;
    int cp = (c & 8) | ((c & 7) ^ (R & 7));
    qf[ks] = *(const s16x8*)&Qs[R * 128 + cp * 8];
  }

  f32x4 O[8] = {};
  f32x4 mrow = {-1e30f, -1e30f, -1e30f, -1e30f};
  f32x4 lrow = {0.f, 0.f, 0.f, 0.f};
  const float scale = 0.088388347648318447f;

  for (int tile = 0; tile <= qt; ++tile) {
    f32x4 sc[4] = {};
#pragma unroll
    for (int ks = 0; ks < 4; ++ks) {
#pragma unroll
      for (int kt = 0; kt < 4; ++kt) {
        int R = kt * 16 + l15;
        int c = ks * 4 + l4;
        int cp = (c & 8) | ((c & 7) ^ (R & 7));
        s16x8 kf = *(const s16x8*)&Ks[R * 128 + cp * 8];
        sc[kt] = MFMA_BF16(qf[ks], kf, sc[kt], 0, 0, 0);
      }
    }
    const bool diag = (tile == qt);
#pragma unroll
    for (int kt = 0; kt < 4; ++kt) {
      int key = kt * 16 + l15;
#pragma unroll
      for (int j = 0; j < 4; ++j) {
        float s = sc[kt][j] * scale;
        if (diag && key > (w * 16 + l4 * 4 + j)) s = -1e30f;
        sc[kt][j] = s;
      }
    }
    f32x4 mt;
#pragma unroll
    for (int j = 0; j < 4; ++j)
      mt[j] = fmaxf(fmaxf(sc[0][j], sc[1][j]), fmaxf(sc[2][j], sc[3][j]));
#pragma unroll
    for (int msk = 1; msk < 16; msk <<= 1)
#pragma unroll
      for (int j = 0; j < 4; ++j) mt[j] = fmaxf(mt[j], __shfl_xor(mt[j], msk));
    f32x4 mnew, rs;
#pragma unroll
    for (int j = 0; j < 4; ++j) {
      mnew[j] = fmaxf(mrow[j], mt[j]);
      rs[j] = __expf(mrow[j] - mnew[j]);
    }
    f32x4 psum = {0.f, 0.f, 0.f, 0.f};
    unsigned short* pw = &Ps[w][0];
#pragma unroll
    for (int kt = 0; kt < 4; ++kt) {
      int kg = kt * 2 + (l15 >> 3), ke = l15 & 7;
#pragma unroll
      for (int j = 0; j < 4; ++j) {
        float p = __expf(sc[kt][j] - mnew[j]);
        psum[j] += p;
        int q = l4 * 4 + j;
        pw[q * 64 + ((kg ^ (q & 7)) * 8) + ke] = f2bf(p);
      }
    }
#pragma unroll
    for (int msk = 1; msk < 16; msk <<= 1)
#pragma unroll
      for (int j = 0; j < 4; ++j) psum[j] += __shfl_xor(psum[j], msk);
    mrow = mnew;
#pragma unroll
    for (int j = 0; j < 4; ++j) lrow[j] = lrow[j] * rs[j] + psum[j];
#pragma unroll
    for (int dt = 0; dt < 8; ++dt) O[dt] *= rs;
#pragma unroll
    for (int js = 0; js < 2; ++js) {
      int cpp = (js * 4 + l4) ^ (l15 & 7);
      s16x8 pf = *(const s16x8*)&Ps[w][l15 * 64 + cpp * 8];
#pragma unroll
      for (int dt = 0; dt < 8; ++dt) {
        int D = dt * 16 + l15;
        s16x8 vf = *(const s16x8*)&Vts[D * 64 + cpp * 8];
        O[dt] = MFMA_BF16(pf, vf, O[dt], 0, 0, 0);
      }
    }
    __syncthreads();
    if (tile < qt) stageKV((tile + 1) * 64);
    __syncthreads();
  }

  f32x4 linv;
#pragma unroll
  for (int j = 0; j < 4; ++j) linv[j] = 1.f / lrow[j];
  const int tok0 = b * 1024 + qs0 + w * 16 + l4 * 4;
#pragma unroll
  for (int dt = 0; dt < 8; ++dt) {
    int d = dt * 16 + l15;
#pragma unroll
    for (int j = 0; j < 4; ++j) {
      size_t zidx = (size_t)(tok0 + j) * 5120 + h * 128 + d;
      size_t aidx = (size_t)(tok0 + j) * 2048 + h * 128 + d;
      float z = bf2f(Zb[zidx]);
      float o = O[dt][j] * linv[j];
      AO[aidx] = f2bf(o / (1.f + __expf(-z)));
    }
  }
}

// ---------------------------------------------------------------------------
// launcher
// ---------------------------------------------------------------------------
extern "C" void kernel_launch(void* const* d_in, const int* in_sizes, int n_in,
                              void* d_out, int out_size, void* d_ws, size_t ws_size,
                              hipStream_t stream) {
  const float* x       = (const float*)d_in[0];
  const float* in_ln   = (const float*)d_in[1];
  const float* Wq      = (const float*)d_in[2];
  const float* Wk      = (const float*)d_in[3];
  const float* Wv      = (const float*)d_in[4];
  const float* Wz      = (const float*)d_in[5];
  const float* Wo      = (const float*)d_in[6];
  const float* qn_w    = (const float*)d_in[7];
  const float* kn_w    = (const float*)d_in[8];
  const float* post_ln = (const float*)d_in[9];
  const float* Wg      = (const float*)d_in[10];
  const float* Wu      = (const float*)d_in[11];
  const float* Wd      = (const float*)d_in[12];

  const int T = 4096;

  char* ws = (char*)d_ws;
  size_t off = 0;
  auto alloc = [&](size_t bytes) -> void* {
    off = (off + 255) & ~(size_t)255;
    void* p = ws + off;
    off += bytes;
    return p;
  };

  unsigned short* Wqkvz_b = (unsigned short*)alloc((size_t)5120 * 2048 * 2);
  unsigned short* Wo_b = (unsigned short*)alloc((size_t)2048 * 2048 * 2);
  unsigned short* Wg_b = (unsigned short*)alloc((size_t)8192 * 2048 * 2);
  unsigned short* Wu_b = (unsigned short*)alloc((size_t)8192 * 2048 * 2);
  unsigned short* Wd_b = (unsigned short*)alloc((size_t)2048 * 8192 * 2);

  char* R = (char*)alloc((size_t)64 * 1024 * 1024);
  unsigned short* qkvz_bf = (unsigned short*)R;
  unsigned short* h_bf    = (unsigned short*)(R + (size_t)40 * 1024 * 1024);
  unsigned short* gu_bf   = (unsigned short*)R;
  unsigned short* ao_bf   = h_bf;

  float* x2 = (float*)alloc((size_t)T * 2048 * 4);
  char* x2c = (char*)x2;
  unsigned short* vt_bf = (unsigned short*)(x2c);
  unsigned short* k_bf  = (unsigned short*)(x2c + 4194304);
  unsigned short* q_bf  = (unsigned short*)(x2c + 8388608);

  unsigned short* h2_bf = (unsigned short*)alloc((size_t)T * 2048 * 2);
  float* cosT = (float*)alloc((size_t)1024 * 64 * 4);
  float* sinT = (float*)alloc((size_t)1024 * 64 * 4);

  // fused weight conversion (8 segments, one launch)
  Cvt8 c;
  c.src[0] = Wq;  c.dst[0] = Wqkvz_b;                         c.n4[0] = 1048576;
  c.src[1] = Wk;  c.dst[1] = Wqkvz_b + (size_t)2048 * 2048;   c.n4[1] = 262144;
  c.src[2] = Wv;  c.dst[2] = Wqkvz_b + (size_t)2560 * 2048;   c.n4[2] = 262144;
  c.src[3] = Wz;  c.dst[3] = Wqkvz_b + (size_t)3072 * 2048;   c.n4[3] = 1048576;
  c.src[4] = Wo;  c.dst[4] = Wo_b;                            c.n4[4] = 1048576;
  c.src[5] = Wg;  c.dst[5] = Wg_b;                            c.n4[5] = 4194304;
  c.src[6] = Wu;  c.dst[6] = Wu_b;                            c.n4[6] = 4194304;
  c.src[7] = Wd;  c.dst[7] = Wd_b;                            c.n4[7] = 4194304;
  k_cvt_all<<<dim3(512, 8), 256, 0, stream>>>(c);

  k_rope_table<<<256, 256, 0, stream>>>(cosT, sinT);

  // h = rmsnorm(x, in_ln)
  k_rmsnorm<<<T, 256, 0, stream>>>(x, in_ln, h_bf);

  // fused QKVZ projection: [4096][5120] bf16 (128² dbuf)
  k_gemm_bt<2><<<dim3(40, 32), 256, 0, stream>>>(h_bf, Wqkvz_b, nullptr, qkvz_bf, nullptr, T, 5120, 2048);

  // per-head q/k RMSNorm + RoPE -> bf16
  k_qknorm_rope<<<20480, 256, 0, stream>>>(qkvz_bf, q_bf, k_bf, qn_w, kn_w, cosT, sinT);

  // V -> V^T bf16 per (b,kv)
  k_transpose_v<<<dim3(16, 4, 4), 256, 0, stream>>>(qkvz_bf, vt_bf);

  // causal GQA attention (MFMA) + sigmoid(z) gate -> ao_bf
  k_attn_mfma<<<dim3(16, 16, 4), 256, 0, stream>>>(q_bf, k_bf, vt_bf, qkvz_bf + 3072, ao_bf);

  // x2 = x + ao @ Wo^T
  k_gemm_bt<1><<<dim3(16, 32), 256, 0, stream>>>(ao_bf, Wo_b, x2, nullptr, x, T, 2048, 2048);

  // h2 = rmsnorm(x2, post_ln)
  k_rmsnorm<<<T, 256, 0, stream>>>(x2, post_ln, h2_bf);

  // gu = h2 @ Wg^T  (bf16, 4-phase 256²)
  k_gemm256<2><<<dim3(32, 16), 512, 0, stream>>>(h2_bf, Wg_b, gu_bf, T, 8192, 2048);

  // gu = silu(gu) * (h2 @ Wu^T)  (in place, 4-phase 256²)
  k_gemm256<4><<<dim3(32, 16), 512, 0, stream>>>(h2_bf, Wu_b, gu_bf, T, 8192, 2048);

  // out = x2 + gu @ Wd^T  (128² dbuf)
  k_gemm_bt<1><<<dim3(16, 32), 256, 0, stream>>>(gu_bf, Wd_b, (float*)d_out, nullptr, x2, T, 2048, 8192);
}

// Round 17
// 831.819 us; speedup vs baseline: 1.0355x; 1.0017x over previous
//
#include <hip/hip_runtime.h>

// ---------------------------------------------------------------------------
// DecoderLayer on MI355X — converged configuration (833 us measured):
//  - k_cvt_all: single fused f32->bf16 weight conversion (8 segments).
//  - k_gemm256 (4-phase, 256x256, BK=64, XOR-swizzle, setprio): Wg, Wu.
//  - k_gemm_bt (128x128, BK=32, dbuf, supertile raster): QKVZ, Wo, Wd.
//  - k_attn_mfma: bf16 MFMA flash attention with fused sigmoid(z) gate.
// ---------------------------------------------------------------------------

typedef __attribute__((ext_vector_type(4))) float  f32x4;
typedef __attribute__((ext_vector_type(8))) short  s16x8;
typedef __attribute__((ext_vector_type(4))) unsigned short u16x4;

#define DEVI static __device__ __forceinline__

DEVI unsigned short f2bf(float f) {
  union { float f; unsigned u; } a; a.f = f;
  unsigned r = a.u + 0x7FFFu + ((a.u >> 16) & 1u);
  return (unsigned short)(r >> 16);
}
DEVI float bf2f(unsigned short u) {
  union { unsigned u; float f; } a; a.u = (unsigned)u << 16; return a.f;
}

DEVI void gload16(const void* g, void* l) {
  __builtin_amdgcn_global_load_lds(
      (const __attribute__((address_space(1))) unsigned int*)(unsigned long long)g,
      (__attribute__((address_space(3))) unsigned int*)(unsigned int)(unsigned long long)l,
      16, 0, 0);
}

#define MFMA_BF16 __builtin_amdgcn_mfma_f32_16x16x32_bf16
#define WAITV8()  asm volatile("s_waitcnt vmcnt(8)" ::: "memory")
#define WAITV0()  asm volatile("s_waitcnt vmcnt(0)" ::: "memory")
#define PIN()     __builtin_amdgcn_sched_barrier(0)
#define LGKM0()   do { asm volatile("s_waitcnt lgkmcnt(0)" ::: "memory"); \
                       __builtin_amdgcn_sched_barrier(0); } while (0)

// ---------------------------------------------------------------------------
// Fused weight conversion: 8 segments, blockIdx.y selects segment.
// ---------------------------------------------------------------------------
struct Cvt8 {
  const float* src[8];
  unsigned short* dst[8];
  int n4[8];
};

__global__ __launch_bounds__(256) void k_cvt_all(Cvt8 c) {
  const int seg = blockIdx.y;
  const f32x4* s = (const f32x4*)c.src[seg];
  u16x4* d = (u16x4*)c.dst[seg];
  const int n = c.n4[seg];
  const int stride = gridDim.x * blockDim.x;
  for (int i = blockIdx.x * blockDim.x + threadIdx.x; i < n; i += stride) {
    f32x4 v = s[i];
    u16x4 o;
    o.x = f2bf(v.x); o.y = f2bf(v.y); o.z = f2bf(v.z); o.w = f2bf(v.w);
    d[i] = o;
  }
}

// ---------------------------------------------------------------------------
__global__ __launch_bounds__(256) void k_rmsnorm(const float* __restrict__ x,
                                                 const float* __restrict__ w,
                                                 unsigned short* __restrict__ out) {
  const int row = blockIdx.x, t = threadIdx.x;
  const f32x4* xr = (const f32x4*)(x + (size_t)row * 2048);
  f32x4 a = xr[t * 2], b = xr[t * 2 + 1];
  float ss = a.x*a.x + a.y*a.y + a.z*a.z + a.w*a.w
           + b.x*b.x + b.y*b.y + b.z*b.z + b.w*b.w;
#pragma unroll
  for (int m = 32; m; m >>= 1) ss += __shfl_xor(ss, m);
  __shared__ float sred[4];
  if ((t & 63) == 0) sred[t >> 6] = ss;
  __syncthreads();
  float tot = sred[0] + sred[1] + sred[2] + sred[3];
  float r = rsqrtf(tot * (1.0f / 2048.0f) + 1e-6f);
  const f32x4* wr = (const f32x4*)w;
  f32x4 w1 = wr[t * 2], w2 = wr[t * 2 + 1];
  u16x4 o1, o2;
  o1.x = f2bf(a.x * r * (1.f + w1.x)); o1.y = f2bf(a.y * r * (1.f + w1.y));
  o1.z = f2bf(a.z * r * (1.f + w1.z)); o1.w = f2bf(a.w * r * (1.f + w1.w));
  o2.x = f2bf(b.x * r * (1.f + w2.x)); o2.y = f2bf(b.y * r * (1.f + w2.y));
  o2.z = f2bf(b.z * r * (1.f + w2.z)); o2.w = f2bf(b.w * r * (1.f + w2.w));
  u16x4* od = (u16x4*)(out + (size_t)row * 2048);
  od[t * 2] = o1; od[t * 2 + 1] = o2;
}

// ---------------------------------------------------------------------------
__global__ void k_rope_table(float* __restrict__ cosT, float* __restrict__ sinT) {
  int i = blockIdx.x * blockDim.x + threadIdx.x;
  int tpos = i >> 6, f = i & 63;
  double inv = exp(-0.14391156831212787 * (double)f);
  float ang = (float)tpos * (float)inv;
  cosT[i] = cosf(ang);
  sinT[i] = sinf(ang);
}

// ---------------------------------------------------------------------------
__global__ __launch_bounds__(256) void k_qknorm_rope(
    const unsigned short* __restrict__ QKVZ,
    unsigned short* __restrict__ Qo, unsigned short* __restrict__ Ko,
    const float* __restrict__ qw, const float* __restrict__ kw,
    const float* __restrict__ cosT, const float* __restrict__ sinT) {
  int gid = blockIdx.x * 4 + (threadIdx.x >> 6);
  int lane = threadIdx.x & 63;
  int tok = gid / 20, hh = gid % 20;
  const unsigned short* p; const float* w; unsigned short* o;
  if (hh < 16) { p = QKVZ + (size_t)tok * 5120 + hh * 128; w = qw;
                 o = Qo + (size_t)tok * 2048 + hh * 128; }
  else         { p = QKVZ + (size_t)tok * 5120 + 2048 + (hh - 16) * 128; w = kw;
                 o = Ko + (size_t)tok * 512 + (hh - 16) * 128; }
  float x1 = bf2f(p[lane]), x2 = bf2f(p[lane + 64]);
  float ss = x1 * x1 + x2 * x2;
#pragma unroll
  for (int m = 1; m < 64; m <<= 1) ss += __shfl_xor(ss, m);
  float r = rsqrtf(ss * (1.0f / 128.0f) + 1e-6f);
  float n1 = x1 * r * (1.f + w[lane]);
  float n2 = x2 * r * (1.f + w[lane + 64]);
  int s = tok & 1023;
  float c = cosT[s * 64 + lane], sn = sinT[s * 64 + lane];
  o[lane]      = f2bf(n1 * c - n2 * sn);
  o[lane + 64] = f2bf(n2 * c + n1 * sn);
}

// ---------------------------------------------------------------------------
__global__ __launch_bounds__(256) void k_transpose_v(const unsigned short* __restrict__ QKVZ,
                                                     unsigned short* __restrict__ Vt) {
  __shared__ unsigned short Vl[128 * 66];
  const int t = threadIdx.x;
  const int key0 = blockIdx.x * 64, kvh = blockIdx.y, b = blockIdx.z;
#pragma unroll
  for (int i = 0; i < 4; ++i) {
    int g = i * 256 + t;
    int key = g >> 4, dc = (g & 15) * 8;
    s16x8 v = *(const s16x8*)&QKVZ[(size_t)(b * 1024 + key0 + key) * 5120 + 2560 + kvh * 128 + dc];
#pragma unroll
    for (int j = 0; j < 8; ++j) Vl[(dc + j) * 66 + key] = (unsigned short)v[j];
  }
  __syncthreads();
#pragma unroll
  for (int i = 0; i < 8; ++i) {
    int g = i * 256 + t;
    int d = g >> 4, kc = g & 15;
    u16x4 o;
#pragma unroll
    for (int j = 0; j < 4; ++j) o[j] = Vl[d * 66 + kc * 4 + j];
    *(u16x4*)&Vt[((size_t)(b * 4 + kvh) * 128 + d) * 1024 + key0 + kc * 4] = o;
  }
}

// ---------------------------------------------------------------------------
// 256x256 GEMM, BK=64, 8 waves, 4-phase/K-tile. Wg + Wu.
// EPI 2: store bf16.  EPI 4: in-place bf16( silu(Cb[idx]) * acc ).
// ---------------------------------------------------------------------------
template <int EPI>
__global__ __launch_bounds__(512) void k_gemm256(
    const unsigned short* __restrict__ A, const unsigned short* __restrict__ B,
    unsigned short* __restrict__ Cb, int M, int N, int K) {
  __shared__ unsigned short As[2][256][64];
  __shared__ unsigned short Bs[2][256][64];

  const int t = threadIdx.x, lane = t & 63, w = t >> 6;
  const int wr = w >> 2, wc = w & 3;
  const int l15 = lane & 15, l4 = lane >> 4;
  const int xg = l15 & 7;
  const int hb = wc >> 1, cl = wc & 1;

  const int nbx = gridDim.x;
  const int nwg = nbx * gridDim.y;
  const int bid = blockIdx.y * nbx + blockIdx.x;
  const int sw = (bid & 7) * (nwg >> 3) + (bid >> 3);
  const int tpg = 8 * nbx;
  const int mi_ = (sw / tpg) * 8 + (sw & 7);
  const int ni_ = (sw % tpg) >> 3;
  const int m0 = mi_ * 256, n0 = ni_ * 256;

  const int NT = K >> 6;

  auto stageA = [&](int tt, int pm) {
    int dd = tt & 1;
#pragma unroll
    for (int c = 0; c < 2; ++c) {
      int r0 = wr * 128 + pm * 64 + wc * 16 + c * 8;
      int r = r0 + (lane >> 3);
      int gs = (lane & 7) ^ (r & 7);
      gload16(A + (size_t)(m0 + r) * K + tt * 64 + gs * 8, (void*)&As[dd][r0][0]);
    }
  };
  auto stageB = [&](int tt, int pn) {
    int dd = tt & 1;
#pragma unroll
    for (int c = 0; c < 2; ++c) {
      int r0 = hb * 128 + cl * 64 + pn * 32 + wr * 16 + c * 8;
      int r = r0 + (lane >> 3);
      int gs = (lane & 7) ^ (r & 7);
      gload16(B + (size_t)(n0 + r) * K + tt * 64 + gs * 8, (void*)&Bs[dd][r0][0]);
    }
  };

  stageA(0, 0); stageB(0, 0); stageB(0, 1); stageA(0, 1);
  stageA(1, 0); stageB(1, 0); stageB(1, 1); stageA(1, 1);

  f32x4 acc[8][4] = {};

  WAITV8();
  __builtin_amdgcn_s_barrier();

  for (int u = 0; u < NT; ++u) {
    const int cur = u & 1;
    const bool deep = (u + 2 < NT);
    s16x8 afL[4][2], afH[4][2], bf0[2][2], bf1[2][2];

#pragma unroll
    for (int i = 0; i < 4; ++i) {
      int row = wr * 128 + i * 16 + l15;
      afL[i][0] = *(const s16x8*)&As[cur][row][(l4 ^ xg) * 8];
      afL[i][1] = *(const s16x8*)&As[cur][row][((l4 ^ xg) ^ 4) * 8];
    }
#pragma unroll
    for (int n = 0; n < 2; ++n) {
      int row = wc * 64 + n * 16 + l15;
      bf0[n][0] = *(const s16x8*)&Bs[cur][row][(l4 ^ xg) * 8];
      bf0[n][1] = *(const s16x8*)&Bs[cur][row][((l4 ^ xg) ^ 4) * 8];
    }
    PIN();
    __builtin_amdgcn_s_barrier();
    LGKM0();
    __builtin_amdgcn_s_setprio(1);
#pragma unroll
    for (int i = 0; i < 4; ++i)
#pragma unroll
      for (int n = 0; n < 2; ++n) {
        acc[i][n] = MFMA_BF16(afL[i][0], bf0[n][0], acc[i][n], 0, 0, 0);
        acc[i][n] = MFMA_BF16(afL[i][1], bf0[n][1], acc[i][n], 0, 0, 0);
      }
    __builtin_amdgcn_s_setprio(0);
    __builtin_amdgcn_s_barrier();

#pragma unroll
    for (int n = 0; n < 2; ++n) {
      int row = wc * 64 + (2 + n) * 16 + l15;
      bf1[n][0] = *(const s16x8*)&Bs[cur][row][(l4 ^ xg) * 8];
      bf1[n][1] = *(const s16x8*)&Bs[cur][row][((l4 ^ xg) ^ 4) * 8];
    }
    if (deep) stageA(u + 2, 0);
    PIN();
    __builtin_amdgcn_s_barrier();
    LGKM0();
    __builtin_amdgcn_s_setprio(1);
#pragma unroll
    for (int i = 0; i < 4; ++i)
#pragma unroll
      for (int n = 0; n < 2; ++n) {
        acc[i][2 + n] = MFMA_BF16(afL[i][0], bf1[n][0], acc[i][2 + n], 0, 0, 0);
        acc[i][2 + n] = MFMA_BF16(afL[i][1], bf1[n][1], acc[i][2 + n], 0, 0, 0);
      }
    __builtin_amdgcn_s_setprio(0);
    __builtin_amdgcn_s_barrier();

#pragma unroll
    for (int i = 0; i < 4; ++i) {
      int row = wr * 128 + 64 + i * 16 + l15;
      afH[i][0] = *(const s16x8*)&As[cur][row][(l4 ^ xg) * 8];
      afH[i][1] = *(const s16x8*)&As[cur][row][((l4 ^ xg) ^ 4) * 8];
    }
    if (deep) { stageB(u + 2, 0); stageB(u + 2, 1); }
    PIN();
    __builtin_amdgcn_s_barrier();
    LGKM0();
    __builtin_amdgcn_s_setprio(1);
#pragma unroll
    for (int i = 0; i < 4; ++i)
#pragma unroll
      for (int n = 0; n < 2; ++n) {
        acc[4 + i][2 + n] = MFMA_BF16(afH[i][0], bf1[n][0], acc[4 + i][2 + n], 0, 0, 0);
        acc[4 + i][2 + n] = MFMA_BF16(afH[i][1], bf1[n][1], acc[4 + i][2 + n], 0, 0, 0);
      }
    __builtin_amdgcn_s_setprio(0);
    __builtin_amdgcn_s_barrier();

    if (deep) stageA(u + 2, 1);
    if (deep) WAITV8(); else WAITV0();
    PIN();
    __builtin_amdgcn_s_barrier();
    __builtin_amdgcn_s_setprio(1);
#pragma unroll
    for (int i = 0; i < 4; ++i)
#pragma unroll
      for (int n = 0; n < 2; ++n) {
        acc[4 + i][n] = MFMA_BF16(afH[i][0], bf0[n][0], acc[4 + i][n], 0, 0, 0);
        acc[4 + i][n] = MFMA_BF16(afH[i][1], bf0[n][1], acc[4 + i][n], 0, 0, 0);
      }
    __builtin_amdgcn_s_setprio(0);
    __builtin_amdgcn_s_barrier();
  }

#pragma unroll
  for (int mi = 0; mi < 8; ++mi)
#pragma unroll
    for (int ni = 0; ni < 4; ++ni) {
      int col = n0 + wc * 64 + ni * 16 + l15;
#pragma unroll
      for (int j = 0; j < 4; ++j) {
        int row = m0 + wr * 128 + mi * 16 + l4 * 4 + j;
        size_t idx = (size_t)row * N + col;
        float g = acc[mi][ni][j];
        if constexpr (EPI == 2) {
          Cb[idx] = f2bf(g);
        } else {
          float gv = bf2f(Cb[idx]);
          float sg = gv / (1.f + __expf(-gv));
          Cb[idx] = f2bf(sg * g);
        }
      }
    }
}

// ---------------------------------------------------------------------------
// 128x128 2-phase dbuf GEMM with granule-XOR swizzle (QKVZ / Wo / Wd).
// EPI 0: f32. EPI 1: f32 + residual. EPI 2: bf16.
// ---------------------------------------------------------------------------
template <int EPI>
__global__ __launch_bounds__(256) void k_gemm_bt(
    const unsigned short* __restrict__ A, const unsigned short* __restrict__ B,
    float* __restrict__ Cf, unsigned short* __restrict__ Cb,
    const float* __restrict__ res,
    int M, int N, int K) {
  __shared__ unsigned short As[2][128 * 32];
  __shared__ unsigned short Bs[2][128 * 32];

  const int t = threadIdx.x, lane = t & 63, w = t >> 6;
  const int wr = w >> 1, wc = w & 1;
  const int l15 = lane & 15, l4 = lane >> 4;
  const int nbx = gridDim.x;
  const int nwg = nbx * gridDim.y;
  const int bid = blockIdx.y * nbx + blockIdx.x;
  const int sw = (bid & 7) * (nwg >> 3) + (bid >> 3);
  const int tpg = 8 * nbx;
  const int mi = (sw / tpg) * 8 + (sw & 7);
  const int ni = (sw % tpg) >> 3;
  const int m0 = mi * 128, n0 = ni * 128;

  f32x4 acc[4][4] = {};

  const int srow = lane >> 2;
  const int scol = (((lane & 3) ^ (srow & 3))) * 8;
  const int rg = (l4 ^ (l15 & 3)) * 8;

  auto stage = [&](int kk, int sel) {
#pragma unroll
    for (int r = 0; r < 2; ++r) {
      int row = 16 * w + srow + 64 * r;
      gload16(A + (size_t)(m0 + row) * K + kk + scol, (void*)&As[sel][w * 512 + r * 2048]);
      gload16(B + (size_t)(n0 + row) * K + kk + scol, (void*)&Bs[sel][w * 512 + r * 2048]);
    }
  };

  stage(0, 0);
  __syncthreads();

  const int nk = K >> 5;
  for (int tk = 0; tk < nk; ++tk) {
    const int cur = tk & 1;
    if (tk + 1 < nk) stage((tk + 1) << 5, cur ^ 1);

    s16x8 af[4], bf_[4];
#pragma unroll
    for (int i = 0; i < 4; ++i) {
      af[i]  = *(const s16x8*)&As[cur][(wr * 64 + i * 16 + l15) * 32 + rg];
      bf_[i] = *(const s16x8*)&Bs[cur][(wc * 64 + i * 16 + l15) * 32 + rg];
    }
#pragma unroll
    for (int mi2 = 0; mi2 < 4; ++mi2)
#pragma unroll
      for (int ni2 = 0; ni2 < 4; ++ni2)
        acc[mi2][ni2] = MFMA_BF16(af[mi2], bf_[ni2], acc[mi2][ni2], 0, 0, 0);
    __syncthreads();
  }

  const int er = (lane >> 4) * 4;
  const int ec = lane & 15;
#pragma unroll
  for (int mi2 = 0; mi2 < 4; ++mi2)
#pragma unroll
    for (int ni2 = 0; ni2 < 4; ++ni2) {
      int col = n0 + wc * 64 + ni2 * 16 + ec;
#pragma unroll
      for (int j = 0; j < 4; ++j) {
        int row = m0 + wr * 64 + mi2 * 16 + er + j;
        size_t idx = (size_t)row * N + col;
        float g = acc[mi2][ni2][j];
        if constexpr (EPI == 0) {
          Cf[idx] = g;
        } else if constexpr (EPI == 1) {
          Cf[idx] = g + res[idx];
        } else if constexpr (EPI == 2) {
          Cb[idx] = f2bf(g);
        } else {
          float gv = bf2f(Cb[idx]);
          float sg = gv / (1.f + __expf(-gv));
          Cb[idx] = f2bf(sg * g);
        }
      }
    }
}

// ---------------------------------------------------------------------------
// Causal GQA attention, bf16 MFMA flash.
// ---------------------------------------------------------------------------
__global__ __launch_bounds__(256) void k_attn_mfma(
    const unsigned short* __restrict__ Qb,
    const unsigned short* __restrict__ Kb,
    const unsigned short* __restrict__ Vt,
    const unsigned short* __restrict__ Zb,
    unsigned short* __restrict__ AO) {
  __shared__ unsigned short Qs[64 * 128];
  __shared__ unsigned short Ks[64 * 128];
  __shared__ unsigned short Vts[128 * 64];
  __shared__ unsigned short Ps[4][16 * 64];

  const int t = threadIdx.x, lane = t & 63, w = t >> 6;
  const int l15 = lane & 15, l4 = lane >> 4;
  const int qt = (int)gridDim.x - 1 - (int)blockIdx.x;
  const int qs0 = qt * 64;
  const int h = blockIdx.y, b = blockIdx.z;
  const int kv = h >> 2;

  {
    const unsigned short* qb = Qb + (size_t)(b * 1024 + qs0) * 2048 + h * 128;
#pragma unroll
    for (int r = 0; r < 4; ++r) {
      int row = r * 16 + w * 4 + (lane >> 4);
      int cp = lane & 15;
      int c = (cp & 8) | ((cp & 7) ^ (row & 7));
      gload16(qb + (size_t)row * 2048 + c * 8, (void*)&Qs[(r * 256 + w * 64) * 8]);
    }
  }

  auto stageKV = [&](int j0) {
    const unsigned short* kb = Kb + (size_t)(b * 1024 + j0) * 512 + kv * 128;
#pragma unroll
    for (int r = 0; r < 4; ++r) {
      int row = r * 16 + w * 4 + (lane >> 4);
      int cp = lane & 15;
      int c = (cp & 8) | ((cp & 7) ^ (row & 7));
      gload16(kb + (size_t)row * 512 + c * 8, (void*)&Ks[(r * 256 + w * 64) * 8]);
    }
    const unsigned short* vb = Vt + (size_t)(b * 4 + kv) * 131072 + j0;
#pragma unroll
    for (int r = 0; r < 4; ++r) {
      int row = r * 32 + w * 8 + (lane >> 3);
      int cp = lane & 7;
      int c = cp ^ (row & 7);
      gload16(vb + (size_t)row * 1024 + c * 8, (void*)&Vts[(r * 256 + w * 64) * 8]);
    }
  };

  stageKV(0);
  __syncthreads();

  s16x8 qf[4];
#pragma unroll
  for (int ks = 0; ks < 4; ++ks) {
    int R = w * 16 + l15;
    int c = ks * 4 + l4;
    int cp = (c & 8) | ((c & 7) ^ (R & 7));
    qf[ks] = *(const s16x8*)&Qs[R * 128 + cp * 8];
  }

  f32x4 O[8] = {};
  f32x4 mrow = {-1e30f, -1e30f, -1e30f, -1e30f};
  f32x4 lrow = {0.f, 0.f, 0.f, 0.f};
  const float scale = 0.088388347648318447f;

  for (int tile = 0; tile <= qt; ++tile) {
    f32x4 sc[4] = {};
#pragma unroll
    for (int ks = 0; ks < 4; ++ks) {
#pragma unroll
      for (int kt = 0; kt < 4; ++kt) {
        int R = kt * 16 + l15;
        int c = ks * 4 + l4;
        int cp = (c & 8) | ((c & 7) ^ (R & 7));
        s16x8 kf = *(const s16x8*)&Ks[R * 128 + cp * 8];
        sc[kt] = MFMA_BF16(qf[ks], kf, sc[kt], 0, 0, 0);
      }
    }
    const bool diag = (tile == qt);
#pragma unroll
    for (int kt = 0; kt < 4; ++kt) {
      int key = kt * 16 + l15;
#pragma unroll
      for (int j = 0; j < 4; ++j) {
        float s = sc[kt][j] * scale;
        if (diag && key > (w * 16 + l4 * 4 + j)) s = -1e30f;
        sc[kt][j] = s;
      }
    }
    f32x4 mt;
#pragma unroll
    for (int j = 0; j < 4; ++j)
      mt[j] = fmaxf(fmaxf(sc[0][j], sc[1][j]), fmaxf(sc[2][j], sc[3][j]));
#pragma unroll
    for (int msk = 1; msk < 16; msk <<= 1)
#pragma unroll
      for (int j = 0; j < 4; ++j) mt[j] = fmaxf(mt[j], __shfl_xor(mt[j], msk));
    f32x4 mnew, rs;
#pragma unroll
    for (int j = 0; j < 4; ++j) {
      mnew[j] = fmaxf(mrow[j], mt[j]);
      rs[j] = __expf(mrow[j] - mnew[j]);
    }
    f32x4 psum = {0.f, 0.f, 0.f, 0.f};
    unsigned short* pw = &Ps[w][0];
#pragma unroll
    for (int kt = 0; kt < 4; ++kt) {
      int kg = kt * 2 + (l15 >> 3), ke = l15 & 7;
#pragma unroll
      for (int j = 0; j < 4; ++j) {
        float p = __expf(sc[kt][j] - mnew[j]);
        psum[j] += p;
        int q = l4 * 4 + j;
        pw[q * 64 + ((kg ^ (q & 7)) * 8) + ke] = f2bf(p);
      }
    }
#pragma unroll
    for (int msk = 1; msk < 16; msk <<= 1)
#pragma unroll
      for (int j = 0; j < 4; ++j) psum[j] += __shfl_xor(psum[j], msk);
    mrow = mnew;
#pragma unroll
    for (int j = 0; j < 4; ++j) lrow[j] = lrow[j] * rs[j] + psum[j];
#pragma unroll
    for (int dt = 0; dt < 8; ++dt) O[dt] *= rs;
#pragma unroll
    for (int js = 0; js < 2; ++js) {
      int cpp = (js * 4 + l4) ^ (l15 & 7);
      s16x8 pf = *(const s16x8*)&Ps[w][l15 * 64 + cpp * 8];
#pragma unroll
      for (int dt = 0; dt < 8; ++dt) {
        int D = dt * 16 + l15;
        s16x8 vf = *(const s16x8*)&Vts[D * 64 + cpp * 8];
        O[dt] = MFMA_BF16(pf, vf, O[dt], 0, 0, 0);
      }
    }
    __syncthreads();
    if (tile < qt) stageKV((tile + 1) * 64);
    __syncthreads();
  }

  f32x4 linv;
#pragma unroll
  for (int j = 0; j < 4; ++j) linv[j] = 1.f / lrow[j];
  const int tok0 = b * 1024 + qs0 + w * 16 + l4 * 4;
#pragma unroll
  for (int dt = 0; dt < 8; ++dt) {
    int d = dt * 16 + l15;
#pragma unroll
    for (int j = 0; j < 4; ++j) {
      size_t zidx = (size_t)(tok0 + j) * 5120 + h * 128 + d;
      size_t aidx = (size_t)(tok0 + j) * 2048 + h * 128 + d;
      float z = bf2f(Zb[zidx]);
      float o = O[dt][j] * linv[j];
      AO[aidx] = f2bf(o / (1.f + __expf(-z)));
    }
  }
}

// ---------------------------------------------------------------------------
// launcher
// ---------------------------------------------------------------------------
extern "C" void kernel_launch(void* const* d_in, const int* in_sizes, int n_in,
                              void* d_out, int out_size, void* d_ws, size_t ws_size,
                              hipStream_t stream) {
  const float* x       = (const float*)d_in[0];
  const float* in_ln   = (const float*)d_in[1];
  const float* Wq      = (const float*)d_in[2];
  const float* Wk      = (const float*)d_in[3];
  const float* Wv      = (const float*)d_in[4];
  const float* Wz      = (const float*)d_in[5];
  const float* Wo      = (const float*)d_in[6];
  const float* qn_w    = (const float*)d_in[7];
  const float* kn_w    = (const float*)d_in[8];
  const float* post_ln = (const float*)d_in[9];
  const float* Wg      = (const float*)d_in[10];
  const float* Wu      = (const float*)d_in[11];
  const float* Wd      = (const float*)d_in[12];

  const int T = 4096;

  char* ws = (char*)d_ws;
  size_t off = 0;
  auto alloc = [&](size_t bytes) -> void* {
    off = (off + 255) & ~(size_t)255;
    void* p = ws + off;
    off += bytes;
    return p;
  };

  unsigned short* Wqkvz_b = (unsigned short*)alloc((size_t)5120 * 2048 * 2);
  unsigned short* Wo_b = (unsigned short*)alloc((size_t)2048 * 2048 * 2);
  unsigned short* Wg_b = (unsigned short*)alloc((size_t)8192 * 2048 * 2);
  unsigned short* Wu_b = (unsigned short*)alloc((size_t)8192 * 2048 * 2);
  unsigned short* Wd_b = (unsigned short*)alloc((size_t)2048 * 8192 * 2);

  char* R = (char*)alloc((size_t)64 * 1024 * 1024);
  unsigned short* qkvz_bf = (unsigned short*)R;
  unsigned short* h_bf    = (unsigned short*)(R + (size_t)40 * 1024 * 1024);
  unsigned short* gu_bf   = (unsigned short*)R;
  unsigned short* ao_bf   = h_bf;

  float* x2 = (float*)alloc((size_t)T * 2048 * 4);
  char* x2c = (char*)x2;
  unsigned short* vt_bf = (unsigned short*)(x2c);
  unsigned short* k_bf  = (unsigned short*)(x2c + 4194304);
  unsigned short* q_bf  = (unsigned short*)(x2c + 8388608);

  unsigned short* h2_bf = (unsigned short*)alloc((size_t)T * 2048 * 2);
  float* cosT = (float*)alloc((size_t)1024 * 64 * 4);
  float* sinT = (float*)alloc((size_t)1024 * 64 * 4);

  // fused weight conversion (8 segments, one launch)
  Cvt8 c;
  c.src[0] = Wq;  c.dst[0] = Wqkvz_b;                         c.n4[0] = 1048576;
  c.src[1] = Wk;  c.dst[1] = Wqkvz_b + (size_t)2048 * 2048;   c.n4[1] = 262144;
  c.src[2] = Wv;  c.dst[2] = Wqkvz_b + (size_t)2560 * 2048;   c.n4[2] = 262144;
  c.src[3] = Wz;  c.dst[3] = Wqkvz_b + (size_t)3072 * 2048;   c.n4[3] = 1048576;
  c.src[4] = Wo;  c.dst[4] = Wo_b;                            c.n4[4] = 1048576;
  c.src[5] = Wg;  c.dst[5] = Wg_b;                            c.n4[5] = 4194304;
  c.src[6] = Wu;  c.dst[6] = Wu_b;                            c.n4[6] = 4194304;
  c.src[7] = Wd;  c.dst[7] = Wd_b;                            c.n4[7] = 4194304;
  k_cvt_all<<<dim3(512, 8), 256, 0, stream>>>(c);

  k_rope_table<<<256, 256, 0, stream>>>(cosT, sinT);

  // h = rmsnorm(x, in_ln)
  k_rmsnorm<<<T, 256, 0, stream>>>(x, in_ln, h_bf);

  // fused QKVZ projection: [4096][5120] bf16 (128² dbuf)
  k_gemm_bt<2><<<dim3(40, 32), 256, 0, stream>>>(h_bf, Wqkvz_b, nullptr, qkvz_bf, nullptr, T, 5120, 2048);

  // per-head q/k RMSNorm + RoPE -> bf16
  k_qknorm_rope<<<20480, 256, 0, stream>>>(qkvz_bf, q_bf, k_bf, qn_w, kn_w, cosT, sinT);

  // V -> V^T bf16 per (b,kv)
  k_transpose_v<<<dim3(16, 4, 4), 256, 0, stream>>>(qkvz_bf, vt_bf);

  // causal GQA attention (MFMA) + sigmoid(z) gate -> ao_bf
  k_attn_mfma<<<dim3(16, 16, 4), 256, 0, stream>>>(q_bf, k_bf, vt_bf, qkvz_bf + 3072, ao_bf);

  // x2 = x + ao @ Wo^T
  k_gemm_bt<1><<<dim3(16, 32), 256, 0, stream>>>(ao_bf, Wo_b, x2, nullptr, x, T, 2048, 2048);

  // h2 = rmsnorm(x2, post_ln)
  k_rmsnorm<<<T, 256, 0, stream>>>(x2, post_ln, h2_bf);

  // gu = h2 @ Wg^T  (bf16, 4-phase 256²)
  k_gemm256<2><<<dim3(32, 16), 512, 0, stream>>>(h2_bf, Wg_b, gu_bf, T, 8192, 2048);

  // gu = silu(gu) * (h2 @ Wu^T)  (in place, 4-phase 256²)
  k_gemm256<4><<<dim3(32, 16), 512, 0, stream>>>(h2_bf, Wu_b, gu_bf, T, 8192, 2048);

  // out = x2 + gu @ Wd^T  (128² dbuf)
  k_gemm_bt<1><<<dim3(16, 32), 256, 0, stream>>>(gu_bf, Wd_b, (float*)d_out, nullptr, x2, T, 2048, 8192);
}